// Round 2
// baseline (1731.457 us; speedup 1.0000x reference)
//
#include <hip/hip_runtime.h>
#include <hip/hip_bf16.h>

typedef __attribute__((ext_vector_type(8))) short short8;
typedef __attribute__((ext_vector_type(4))) float floatx4;

#define SEQ     2048
#define DMODEL  768
#define DINNER  1536
#define DSTATE  128
#define NH      24
#define CONVDIM 1792
#define NPROJ   3352   // 2*DINNER + 2*DSTATE + NH

// ---------------------------------------------------------------- converts
__global__ __launch_bounds__(256) void cvt_kernel(const float* __restrict__ src,
                                                  __hip_bfloat16* __restrict__ dst, int n) {
    int i = blockIdx.x * 256 + threadIdx.x;
    if (i < n) dst[i] = __float2bfloat16(src[i]);
}

// Build A1[dir][b*SEQ+t][k] = bf16(x[b][dir? SEQ-1-t : t][k])
__global__ __launch_bounds__(256) void prep_x_kernel(const float* __restrict__ x,
                                                     __hip_bfloat16* __restrict__ A1) {
    size_t idx = (size_t)blockIdx.x * 256 + threadIdx.x;
    const size_t total = (size_t)2 * 2 * SEQ * DMODEL;
    if (idx >= total) return;
    int k = (int)(idx % DMODEL);
    size_t m = idx / DMODEL;
    int dir = (int)(m >> 12);          // 4096 rows per dir
    int mm  = (int)(m & 4095);
    int b = mm >> 11, t = mm & 2047;
    int ts = dir ? (SEQ - 1 - t) : t;
    A1[idx] = __float2bfloat16(x[((size_t)(b * SEQ + ts)) * DMODEL + k]);
}

// ---------------------------------------------------------------- GEMM: C = A[M,K] @ Bw[N,K]^T
// mode 0: C[M,N] fp32 store. mode 1: C[flip(row)] += v (bwd out_proj).
// mode 2: in_proj routing epilogue -> Zb (bf16), Xb (bf16), DT/DA (fp32, softplus+exp fused)
__global__ __launch_bounds__(256) void gemm_bt(const __hip_bfloat16* __restrict__ A,
                                               const __hip_bfloat16* __restrict__ Bw,
                                               float* __restrict__ C,
                                               __hip_bfloat16* __restrict__ Zb,
                                               __hip_bfloat16* __restrict__ Xb,
                                               float* __restrict__ DT,
                                               float* __restrict__ DA,
                                               const float* __restrict__ dtbias,
                                               const float* __restrict__ Alog,
                                               int M, int N, int K, int mode) {
    __shared__ __hip_bfloat16 As[64][40];   // pitch 40 -> 2-way bank alias only (free)
    __shared__ __hip_bfloat16 Bs[64][40];
    int tid = threadIdx.x;
    int m0 = blockIdx.y * 64, n0 = blockIdx.x * 64;
    int w = tid >> 6, lane = tid & 63;
    int q = lane >> 4, mm = lane & 15;
    int srow = tid >> 2, scol = (tid & 3) * 8;
    int ar = m0 + srow;                       // always < M (M multiple of 64)
    int br = n0 + srow; if (br > N - 1) br = N - 1;   // clamp (dup rows; cols skipped on store)

    floatx4 acc[4];
#pragma unroll
    for (int i = 0; i < 4; i++) acc[i] = (floatx4){0.f, 0.f, 0.f, 0.f};

    for (int k0 = 0; k0 < K; k0 += 32) {
        short8 av = *(const short8*)(A  + (size_t)ar * K + k0 + scol);
        short8 bv = *(const short8*)(Bw + (size_t)br * K + k0 + scol);
        *(short8*)(&As[srow][scol]) = av;
        *(short8*)(&Bs[srow][scol]) = bv;
        __syncthreads();
        short8 af = *(const short8*)(&As[w * 16 + mm][q * 8]);
#pragma unroll
        for (int cb = 0; cb < 4; cb++) {
            short8 bf = *(const short8*)(&Bs[cb * 16 + mm][q * 8]);
            acc[cb] = __builtin_amdgcn_mfma_f32_16x16x32_bf16(af, bf, acc[cb], 0, 0, 0);
        }
        __syncthreads();
    }

    int row = m0 + w * 16 + q * 4;
#pragma unroll
    for (int cb = 0; cb < 4; cb++) {
        int col = n0 + cb * 16 + mm;
        if (col >= N) continue;
#pragma unroll
        for (int r = 0; r < 4; r++) {
            int rr = row + r;
            float v = acc[cb][r];
            if (mode == 0) {
                C[(size_t)rr * N + col] = v;
            } else if (mode == 1) {
                int b = rr >> 11, t = rr & 2047;
                int orow = (b << 11) + (2047 - t);
                C[(size_t)orow * N + col] += v;
            } else {
                if (col < DINNER) {
                    Zb[(size_t)rr * DINNER + col] = __float2bfloat16(v);
                } else if (col < DINNER + CONVDIM) {
                    Xb[(size_t)rr * CONVDIM + (col - DINNER)] = __float2bfloat16(v);
                } else {
                    int hh = col - (DINNER + CONVDIM);
                    float raw = v + dtbias[hh];
                    float dtv = (raw > 20.f) ? raw : log1pf(__expf(raw));
                    float dAv = __expf(dtv * (-__expf(Alog[hh])));
                    DT[(size_t)rr * NH + hh] = dtv;
                    DA[(size_t)rr * NH + hh] = dAv;
                }
            }
        }
    }
}

// ---------------------------------------------------------------- conv (depthwise K=4) + silu
// Xb layout: [db*SEQ + t][CONVDIM] bf16, t already in (possibly flipped) sequence order.
__global__ __launch_bounds__(256) void conv_kernel(const __hip_bfloat16* __restrict__ Xb,
                                                   const float* __restrict__ conv_w,
                                                   const float* __restrict__ conv_b,
                                                   __hip_bfloat16* __restrict__ xh,
                                                   float* __restrict__ Bm,
                                                   float* __restrict__ Cm) {
    int db  = blockIdx.x >> 6;            // 4 of these
    int dir = db >> 1;
    int t0  = (blockIdx.x & 63) * 32;
    for (int tt = 0; tt < 32; tt++) {
        int t = t0 + tt;
        for (int c = threadIdx.x; c < CONVDIM; c += 256) {
            float acc = conv_b[dir * CONVDIM + c];
#pragma unroll
            for (int k = 0; k < 4; k++) {
                int ts = t - 3 + k;
                float v = (ts >= 0) ? __bfloat162float(Xb[((size_t)db * SEQ + ts) * CONVDIM + c]) : 0.f;
                acc += v * conv_w[((size_t)dir * CONVDIM + c) * 4 + k];
            }
            float sv = acc / (1.f + __expf(-acc));   // silu
            if (c < DINNER)
                xh[((size_t)db * SEQ + t) * DINNER + c] = __float2bfloat16(sv);
            else if (c < DINNER + DSTATE)
                Bm[((size_t)db * SEQ + t) * DSTATE + (c - DINNER)] = sv;
            else
                Cm[((size_t)db * SEQ + t) * DSTATE + (c - DINNER - DSTATE)] = sv;
        }
    }
}

// ---------------------------------------------------------------- sequential scan
// block = (db, head); 4 waves, wave w owns n-quarter [w*32, w*32+32); lane = p (0..63).
__global__ __launch_bounds__(256) void scan_kernel(const __hip_bfloat16* __restrict__ xh,
                                                   const float* __restrict__ Bm,
                                                   const float* __restrict__ Cm,
                                                   const float* __restrict__ dtb,
                                                   const float* __restrict__ dAb,
                                                   float* __restrict__ y) {
    int blk = blockIdx.x;
    int db = blk / NH, hh = blk % NH;
    int tid = threadIdx.x;
    int w = __builtin_amdgcn_readfirstlane(tid >> 6);   // provably wave-uniform
    int p = tid & 63;

    const __hip_bfloat16* xhp = xh + ((size_t)db * SEQ) * DINNER + hh * 64 + p;
    const float* Bp  = Bm + ((size_t)db * SEQ) * DSTATE + w * 32;
    const float* Cp  = Cm + ((size_t)db * SEQ) * DSTATE + w * 32;
    const float* dtp = dtb + (size_t)db * SEQ * NH + hh;
    const float* dAp = dAb + (size_t)db * SEQ * NH + hh;
    float* yp = y + ((size_t)db * SEQ) * DINNER + hh * 64 + p;

    float hs[32];
#pragma unroll
    for (int j = 0; j < 32; j++) hs[j] = 0.f;

    __shared__ float red[2][4][64];

#pragma unroll 2
    for (int t = 0; t < SEQ; t++) {
        const float4* Bq = (const float4*)(Bp + (size_t)t * DSTATE);
        const float4* Cq = (const float4*)(Cp + (size_t)t * DSTATE);
        float xv  = __bfloat162float(xhp[(size_t)t * DINNER]);
        float dtv = dtp[(size_t)t * NH];
        float dAv = dAp[(size_t)t * NH];
        float dtx = dtv * xv;
        float yacc = 0.f;
#pragma unroll
        for (int j4 = 0; j4 < 8; j4++) {
            float4 b4 = Bq[j4];
            float4 c4 = Cq[j4];
            hs[j4 * 4 + 0] = fmaf(hs[j4 * 4 + 0], dAv, dtx * b4.x); yacc = fmaf(hs[j4 * 4 + 0], c4.x, yacc);
            hs[j4 * 4 + 1] = fmaf(hs[j4 * 4 + 1], dAv, dtx * b4.y); yacc = fmaf(hs[j4 * 4 + 1], c4.y, yacc);
            hs[j4 * 4 + 2] = fmaf(hs[j4 * 4 + 2], dAv, dtx * b4.z); yacc = fmaf(hs[j4 * 4 + 2], c4.z, yacc);
            hs[j4 * 4 + 3] = fmaf(hs[j4 * 4 + 3], dAv, dtx * b4.w); yacc = fmaf(hs[j4 * 4 + 3], c4.w, yacc);
        }
        red[t & 1][w][p] = yacc;
        __syncthreads();
        if (w == 0) {
            float s = red[t & 1][0][p] + red[t & 1][1][p] + red[t & 1][2][p] + red[t & 1][3][p];
            yp[(size_t)t * DINNER] = s;
        }
        // double-buffered on t&1: next write to this slot happens after the t+1 barrier -> safe
    }
}

// ---------------------------------------------------------------- gating + RMSNorm -> bf16 A2 (in-place over Z)
__global__ __launch_bounds__(256) void gate_kernel(const float* __restrict__ y,
                                                   const __hip_bfloat16* __restrict__ xh,
                                                   const __hip_bfloat16* __restrict__ Zb,
                                                   const float* __restrict__ Dp,
                                                   const float* __restrict__ norm_w,
                                                   __hip_bfloat16* __restrict__ A2) {
    int row = blockIdx.x;           // db*SEQ + t, 0..8191
    int db = row >> 11;
    int dir = db >> 1;
    const float* yr = y  + (size_t)row * DINNER;
    const __hip_bfloat16* xr = xh + (size_t)row * DINNER;
    const __hip_bfloat16* zr = Zb + (size_t)row * DINNER;

    float vals[6];
    float ss = 0.f;
#pragma unroll
    for (int i = 0; i < 6; i++) {
        int c = threadIdx.x + i * 256;
        float v = yr[c] + Dp[dir * NH + (c >> 6)] * __bfloat162float(xr[c]);
        float z = __bfloat162float(zr[c]);
        v *= z / (1.f + __expf(-z));
        vals[i] = v;
        ss += v * v;
    }
    // reduce over 256 threads (all reads of zr complete before A2 writes within this thread,
    // and rows are block-private -> in-place A2==Zb is safe)
#pragma unroll
    for (int off = 32; off; off >>= 1) ss += __shfl_down(ss, off);
    __shared__ float ls[4];
    if ((threadIdx.x & 63) == 0) ls[threadIdx.x >> 6] = ss;
    __syncthreads();
    float tot = ls[0] + ls[1] + ls[2] + ls[3];
    float scale = rsqrtf(tot / (float)DINNER + 1e-5f);
#pragma unroll
    for (int i = 0; i < 6; i++) {
        int c = threadIdx.x + i * 256;
        A2[(size_t)row * DINNER + c] = __float2bfloat16(vals[i] * scale * norm_w[dir * DINNER + c]);
    }
}

// ---------------------------------------------------------------- launch
extern "C" void kernel_launch(void* const* d_in, const int* in_sizes, int n_in,
                              void* d_out, int out_size, void* d_ws, size_t ws_size,
                              hipStream_t stream) {
    const float* x        = (const float*)d_in[0];
    const float* in_w     = (const float*)d_in[1];
    const float* conv_w   = (const float*)d_in[2];
    const float* conv_b   = (const float*)d_in[3];
    const float* dt_bias  = (const float*)d_in[4];
    const float* A_log    = (const float*)d_in[5];
    const float* Dp       = (const float*)d_in[6];
    const float* norm_w   = (const float*)d_in[7];
    const float* out_w    = (const float*)d_in[8];
    float* out = (float*)d_out;

    // ---- workspace layout (aliased, ~112 MB total) ----
    const size_t szW2 = (size_t)2 * DMODEL * DINNER * 2;   //  4,718,592
    const size_t szZ  = (size_t)8192 * DINNER * 2;         // 25,165,824 (also A2, in-place)
    const size_t szXH = (size_t)8192 * DINNER * 2;         // 25,165,824
    const size_t szBM = (size_t)8192 * DSTATE * 4;         //  4,194,304
    const size_t szCM = szBM;
    const size_t szDT = (size_t)8192 * NH * 4;             //    786,432
    const size_t szDA = szDT;
    const size_t szA1 = (size_t)8192 * DMODEL * 2;         // 12,582,912
    const size_t szW1 = (size_t)2 * NPROJ * DMODEL * 2;    // 10,297,344
    const size_t szXB = (size_t)8192 * CONVDIM * 2;        // 29,360,128
    const size_t szY  = (size_t)8192 * DINNER * 4;         // 50,331,648
    const size_t szR  = (szA1 + szW1 + szXB) > szY ? (szA1 + szW1 + szXB) : szY;

    char* ws = (char*)d_ws;
    size_t off = 0;
    auto alloc = [&](size_t bytes) { char* p = ws + off; off += (bytes + 255) & ~(size_t)255; return p; };

    __hip_bfloat16* W2 = (__hip_bfloat16*)alloc(szW2);
    __hip_bfloat16* Z  = (__hip_bfloat16*)alloc(szZ);
    __hip_bfloat16* XH = (__hip_bfloat16*)alloc(szXH);
    float* BM = (float*)alloc(szBM);
    float* CM = (float*)alloc(szCM);
    float* DT = (float*)alloc(szDT);
    float* DA = (float*)alloc(szDA);
    char*  R  = (char*)alloc(szR);
    // region R: [A1 | W1 | XBC] (dead after conv)  overlaid later by  Y (fp32, written by scan)
    __hip_bfloat16* A1  = (__hip_bfloat16*)R;
    __hip_bfloat16* W1  = (__hip_bfloat16*)(R + szA1);
    __hip_bfloat16* XBC = (__hip_bfloat16*)(R + szA1 + szW1);
    float* Y = (float*)R;

    if (off > ws_size) return;   // clean fail (absmax) instead of OOB crash — diagnostic

    // 1. weight converts
    int n1 = 2 * NPROJ * DMODEL;
    cvt_kernel<<<(n1 + 255) / 256, 256, 0, stream>>>(in_w, W1, n1);
    int n2 = 2 * DMODEL * DINNER;
    cvt_kernel<<<(n2 + 255) / 256, 256, 0, stream>>>(out_w, W2, n2);
    // 2. x -> bf16 (flipped copy for dir 1)
    int n3 = 2 * 4096 * DMODEL;
    prep_x_kernel<<<(n3 + 255) / 256, 256, 0, stream>>>(x, A1);

    // 3. in_proj GEMMs (per dir) with routing epilogue
    {
        dim3 grid((NPROJ + 63) / 64, 4096 / 64);
        for (int dir = 0; dir < 2; dir++) {
            gemm_bt<<<grid, 256, 0, stream>>>(A1 + (size_t)dir * 4096 * DMODEL,
                                              W1 + (size_t)dir * NPROJ * DMODEL,
                                              nullptr,
                                              Z   + (size_t)dir * 4096 * DINNER,
                                              XBC + (size_t)dir * 4096 * CONVDIM,
                                              DT  + (size_t)dir * 4096 * NH,
                                              DA  + (size_t)dir * 4096 * NH,
                                              dt_bias + dir * NH,
                                              A_log   + dir * NH,
                                              4096, NPROJ, DMODEL, 2);
        }
    }

    // 4. conv + silu
    conv_kernel<<<4 * (SEQ / 32), 256, 0, stream>>>(XBC, conv_w, conv_b, XH, BM, CM);

    // 5. sequential scan (Y overlays A1/W1/XBC — all dead now)
    scan_kernel<<<4 * NH, 256, 0, stream>>>(XH, BM, CM, DT, DA, Y);

    // 6. gating + RMSNorm (A2 == Z, in-place)
    gate_kernel<<<2 * 4096, 256, 0, stream>>>(Y, XH, Z, Dp, norm_w, Z);

    // 7. out_proj GEMMs; dir0 overwrites, dir1 flip-adds (same stream -> ordered)
    {
        dim3 grid(DMODEL / 64, 4096 / 64);
        gemm_bt<<<grid, 256, 0, stream>>>(Z, W2, out,
                                          nullptr, nullptr, nullptr, nullptr, nullptr, nullptr,
                                          4096, DMODEL, DINNER, 0);
        gemm_bt<<<grid, 256, 0, stream>>>(Z + (size_t)4096 * DINNER,
                                          W2 + (size_t)DMODEL * DINNER,
                                          out,
                                          nullptr, nullptr, nullptr, nullptr, nullptr, nullptr,
                                          4096, DMODEL, DINNER, 1);
    }
}

// Round 3
// 1598.117 us; speedup vs baseline: 1.0834x; 1.0834x over previous
//
#include <hip/hip_runtime.h>
#include <hip/hip_bf16.h>

typedef __attribute__((ext_vector_type(8))) short short8;
typedef __attribute__((ext_vector_type(4))) float floatx4;

#define SEQ     2048
#define DMODEL  768
#define DINNER  1536
#define DSTATE  128
#define NH      24
#define CONVDIM 1792
#define NPROJ   3352   // 2*DINNER + 2*DSTATE + NH

// ---------------------------------------------------------------- converts
__global__ __launch_bounds__(256) void cvt_kernel(const float* __restrict__ src,
                                                  __hip_bfloat16* __restrict__ dst, int n) {
    int i = blockIdx.x * 256 + threadIdx.x;
    if (i < n) dst[i] = __float2bfloat16(src[i]);
}

// Build A1[dir][b*SEQ+t][k] = bf16(x[b][dir? SEQ-1-t : t][k])
__global__ __launch_bounds__(256) void prep_x_kernel(const float* __restrict__ x,
                                                     __hip_bfloat16* __restrict__ A1) {
    size_t idx = (size_t)blockIdx.x * 256 + threadIdx.x;
    const size_t total = (size_t)2 * 2 * SEQ * DMODEL;
    if (idx >= total) return;
    int k = (int)(idx % DMODEL);
    size_t m = idx / DMODEL;
    int dir = (int)(m >> 12);          // 4096 rows per dir
    int mm  = (int)(m & 4095);
    int b = mm >> 11, t = mm & 2047;
    int ts = dir ? (SEQ - 1 - t) : t;
    A1[idx] = __float2bfloat16(x[((size_t)(b * SEQ + ts)) * DMODEL + k]);
}

// ---------------------------------------------------------------- GEMM: C = A[M,K] @ Bw[N,K]^T
// mode 0: C[M,N] fp32 store. mode 1: C[flip(row)] += v (bwd out_proj).
// mode 2: in_proj routing epilogue -> Zb (bf16), Xb (bf16), DT/DA (fp32, softplus+exp fused)
__global__ __launch_bounds__(256) void gemm_bt(const __hip_bfloat16* __restrict__ A,
                                               const __hip_bfloat16* __restrict__ Bw,
                                               float* __restrict__ C,
                                               __hip_bfloat16* __restrict__ Zb,
                                               __hip_bfloat16* __restrict__ Xb,
                                               float* __restrict__ DT,
                                               float* __restrict__ DA,
                                               const float* __restrict__ dtbias,
                                               const float* __restrict__ Alog,
                                               int M, int N, int K, int mode) {
    __shared__ __hip_bfloat16 As[64][40];   // pitch 40 -> 2-way bank alias only (free)
    __shared__ __hip_bfloat16 Bs[64][40];
    int tid = threadIdx.x;
    int m0 = blockIdx.y * 64, n0 = blockIdx.x * 64;
    int w = tid >> 6, lane = tid & 63;
    int q = lane >> 4, mm = lane & 15;
    int srow = tid >> 2, scol = (tid & 3) * 8;
    int ar = m0 + srow;                       // always < M (M multiple of 64)
    int br = n0 + srow; if (br > N - 1) br = N - 1;   // clamp (dup rows; cols skipped on store)

    floatx4 acc[4];
#pragma unroll
    for (int i = 0; i < 4; i++) acc[i] = (floatx4){0.f, 0.f, 0.f, 0.f};

    for (int k0 = 0; k0 < K; k0 += 32) {
        short8 av = *(const short8*)(A  + (size_t)ar * K + k0 + scol);
        short8 bv = *(const short8*)(Bw + (size_t)br * K + k0 + scol);
        *(short8*)(&As[srow][scol]) = av;
        *(short8*)(&Bs[srow][scol]) = bv;
        __syncthreads();
        short8 af = *(const short8*)(&As[w * 16 + mm][q * 8]);
#pragma unroll
        for (int cb = 0; cb < 4; cb++) {
            short8 bf = *(const short8*)(&Bs[cb * 16 + mm][q * 8]);
            acc[cb] = __builtin_amdgcn_mfma_f32_16x16x32_bf16(af, bf, acc[cb], 0, 0, 0);
        }
        __syncthreads();
    }

    int row = m0 + w * 16 + q * 4;
#pragma unroll
    for (int cb = 0; cb < 4; cb++) {
        int col = n0 + cb * 16 + mm;
        if (col >= N) continue;
#pragma unroll
        for (int r = 0; r < 4; r++) {
            int rr = row + r;
            float v = acc[cb][r];
            if (mode == 0) {
                C[(size_t)rr * N + col] = v;
            } else if (mode == 1) {
                int b = rr >> 11, t = rr & 2047;
                int orow = (b << 11) + (2047 - t);
                C[(size_t)orow * N + col] += v;
            } else {
                if (col < DINNER) {
                    Zb[(size_t)rr * DINNER + col] = __float2bfloat16(v);
                } else if (col < DINNER + CONVDIM) {
                    Xb[(size_t)rr * CONVDIM + (col - DINNER)] = __float2bfloat16(v);
                } else {
                    int hh = col - (DINNER + CONVDIM);
                    float raw = v + dtbias[hh];
                    float dtv = (raw > 20.f) ? raw : log1pf(__expf(raw));
                    float dAv = __expf(dtv * (-__expf(Alog[hh])));
                    DT[(size_t)rr * NH + hh] = dtv;
                    DA[(size_t)rr * NH + hh] = dAv;
                }
            }
        }
    }
}

// ---------------------------------------------------------------- conv (depthwise K=4) + silu
__global__ __launch_bounds__(256) void conv_kernel(const __hip_bfloat16* __restrict__ Xb,
                                                   const float* __restrict__ conv_w,
                                                   const float* __restrict__ conv_b,
                                                   __hip_bfloat16* __restrict__ xh,
                                                   float* __restrict__ Bm,
                                                   float* __restrict__ Cm) {
    int db  = blockIdx.x >> 8;            // 4 of these
    int dir = db >> 1;
    int t0  = (blockIdx.x & 255) * 8;
    for (int tt = 0; tt < 8; tt++) {
        int t = t0 + tt;
        for (int c = threadIdx.x; c < CONVDIM; c += 256) {
            float acc = conv_b[dir * CONVDIM + c];
#pragma unroll
            for (int k = 0; k < 4; k++) {
                int ts = t - 3 + k;
                float v = (ts >= 0) ? __bfloat162float(Xb[((size_t)db * SEQ + ts) * CONVDIM + c]) : 0.f;
                acc += v * conv_w[((size_t)dir * CONVDIM + c) * 4 + k];
            }
            float sv = acc / (1.f + __expf(-acc));   // silu
            if (c < DINNER)
                xh[((size_t)db * SEQ + t) * DINNER + c] = __float2bfloat16(sv);
            else if (c < DINNER + DSTATE)
                Bm[((size_t)db * SEQ + t) * DSTATE + (c - DINNER)] = sv;
            else
                Cm[((size_t)db * SEQ + t) * DSTATE + (c - DINNER - DSTATE)] = sv;
        }
    }
}

// ---------------------------------------------------------------- sequential scan, barrier-free
// 1 wave per block. blk = ((db*NH + hh)*2 + nhalf)*4 + pq.
// lane l: p = pq*16 + (l>>2); owns 16 states n = nhalf*64 + (l&3)*16 .. +16.
// y partial (over 64 n) reduced via shfl_xor over lanes sharing p; two n-halves
// write separate bf16 buffers Y0/Y1, summed in gate_kernel.
__global__ __launch_bounds__(64) void scan_kernel(const __hip_bfloat16* __restrict__ xh,
                                                  const float* __restrict__ Bm,
                                                  const float* __restrict__ Cm,
                                                  const float* __restrict__ dtb,
                                                  const float* __restrict__ dAb,
                                                  __hip_bfloat16* __restrict__ Y0,
                                                  __hip_bfloat16* __restrict__ Y1) {
    int blk = blockIdx.x;
    int pq = blk & 3;
    int nh = (blk >> 2) & 1;
    int t1 = blk >> 3;
    int hh = t1 % NH, db = t1 / NH;
    int l = threadIdx.x;
    int p  = pq * 16 + (l >> 2);
    int nb = nh * 64 + (l & 3) * 16;

    const float* Bp = Bm + (size_t)db * SEQ * DSTATE + nb;
    const float* Cp = Cm + (size_t)db * SEQ * DSTATE + nb;
    const __hip_bfloat16* xp = xh + (size_t)db * SEQ * DINNER + hh * 64 + p;
    const float* dtp = dtb + (size_t)db * SEQ * NH + hh;
    const float* dAp = dAb + (size_t)db * SEQ * NH + hh;
    __hip_bfloat16* yp = (nh ? Y1 : Y0) + (size_t)db * SEQ * DINNER + hh * 64 + p;

    float hs[16];
#pragma unroll
    for (int j = 0; j < 16; j++) hs[j] = 0.f;

    // prologue: load t=0
    float4 b[4], c[4];
    float xv, dtv, dAv;
#pragma unroll
    for (int j = 0; j < 4; j++) {
        b[j] = *(const float4*)(Bp + j * 4);
        c[j] = *(const float4*)(Cp + j * 4);
    }
    xv  = __bfloat162float(xp[0]);
    dtv = dtp[0];
    dAv = dAp[0];

#pragma unroll 2
    for (int t = 0; t < SEQ; t++) {
        // issue prefetch for t+1 (clamped) before consuming current regs
        int tn = (t + 1 < SEQ) ? (t + 1) : t;
        float4 pb[4], pc[4];
#pragma unroll
        for (int j = 0; j < 4; j++) {
            pb[j] = *(const float4*)(Bp + (size_t)tn * DSTATE + j * 4);
            pc[j] = *(const float4*)(Cp + (size_t)tn * DSTATE + j * 4);
        }
        float pxv  = __bfloat162float(xp[(size_t)tn * DINNER]);
        float pdt  = dtp[(size_t)tn * NH];
        float pdA  = dAp[(size_t)tn * NH];

        float dtx = dtv * xv;
        float yac = 0.f;
#pragma unroll
        for (int j4 = 0; j4 < 4; j4++) {
            hs[j4 * 4 + 0] = fmaf(hs[j4 * 4 + 0], dAv, dtx * b[j4].x); yac = fmaf(hs[j4 * 4 + 0], c[j4].x, yac);
            hs[j4 * 4 + 1] = fmaf(hs[j4 * 4 + 1], dAv, dtx * b[j4].y); yac = fmaf(hs[j4 * 4 + 1], c[j4].y, yac);
            hs[j4 * 4 + 2] = fmaf(hs[j4 * 4 + 2], dAv, dtx * b[j4].z); yac = fmaf(hs[j4 * 4 + 2], c[j4].z, yac);
            hs[j4 * 4 + 3] = fmaf(hs[j4 * 4 + 3], dAv, dtx * b[j4].w); yac = fmaf(hs[j4 * 4 + 3], c[j4].w, yac);
        }
        // reduce over the 4 lanes sharing p (l^1, l^2)
        yac += __shfl_xor(yac, 1, 64);
        yac += __shfl_xor(yac, 2, 64);
        if ((l & 3) == 0) yp[(size_t)t * DINNER] = __float2bfloat16(yac);

#pragma unroll
        for (int j = 0; j < 4; j++) { b[j] = pb[j]; c[j] = pc[j]; }
        xv = pxv; dtv = pdt; dAv = pdA;
    }
}

// ---------------------------------------------------------------- gating + RMSNorm -> bf16 A2 (in-place over Z)
__global__ __launch_bounds__(256) void gate_kernel(const __hip_bfloat16* __restrict__ Y0,
                                                   const __hip_bfloat16* __restrict__ Y1,
                                                   const __hip_bfloat16* __restrict__ xh,
                                                   const __hip_bfloat16* __restrict__ Zb,
                                                   const float* __restrict__ Dp,
                                                   const float* __restrict__ norm_w,
                                                   __hip_bfloat16* __restrict__ A2) {
    int row = blockIdx.x;           // db*SEQ + t, 0..8191
    int db = row >> 11;
    int dir = db >> 1;
    const __hip_bfloat16* y0 = Y0 + (size_t)row * DINNER;
    const __hip_bfloat16* y1 = Y1 + (size_t)row * DINNER;
    const __hip_bfloat16* xr = xh + (size_t)row * DINNER;
    const __hip_bfloat16* zr = Zb + (size_t)row * DINNER;

    float vals[6];
    float ss = 0.f;
#pragma unroll
    for (int i = 0; i < 6; i++) {
        int c = threadIdx.x + i * 256;
        float yv = __bfloat162float(y0[c]) + __bfloat162float(y1[c]);
        float v = yv + Dp[dir * NH + (c >> 6)] * __bfloat162float(xr[c]);
        float z = __bfloat162float(zr[c]);
        v *= z / (1.f + __expf(-z));
        vals[i] = v;
        ss += v * v;
    }
#pragma unroll
    for (int off = 32; off; off >>= 1) ss += __shfl_down(ss, off);
    __shared__ float ls[4];
    if ((threadIdx.x & 63) == 0) ls[threadIdx.x >> 6] = ss;
    __syncthreads();
    float tot = ls[0] + ls[1] + ls[2] + ls[3];
    float scale = rsqrtf(tot / (float)DINNER + 1e-5f);
#pragma unroll
    for (int i = 0; i < 6; i++) {
        int c = threadIdx.x + i * 256;
        A2[(size_t)row * DINNER + c] = __float2bfloat16(vals[i] * scale * norm_w[dir * DINNER + c]);
    }
}

// ---------------------------------------------------------------- launch
extern "C" void kernel_launch(void* const* d_in, const int* in_sizes, int n_in,
                              void* d_out, int out_size, void* d_ws, size_t ws_size,
                              hipStream_t stream) {
    const float* x        = (const float*)d_in[0];
    const float* in_w     = (const float*)d_in[1];
    const float* conv_w   = (const float*)d_in[2];
    const float* conv_b   = (const float*)d_in[3];
    const float* dt_bias  = (const float*)d_in[4];
    const float* A_log    = (const float*)d_in[5];
    const float* Dp       = (const float*)d_in[6];
    const float* norm_w   = (const float*)d_in[7];
    const float* out_w    = (const float*)d_in[8];
    float* out = (float*)d_out;

    // ---- workspace layout (aliased, ~117 MB total) ----
    const size_t szW2 = (size_t)2 * DMODEL * DINNER * 2;   //  4,718,592
    const size_t szZ  = (size_t)8192 * DINNER * 2;         // 25,165,824 (also A2, in-place)
    const size_t szXH = (size_t)8192 * DINNER * 2;         // 25,165,824
    const size_t szBM = (size_t)8192 * DSTATE * 4;         //  4,194,304
    const size_t szCM = szBM;
    const size_t szDT = (size_t)8192 * NH * 4;             //    786,432
    const size_t szDA = szDT;
    const size_t szA1 = (size_t)8192 * DMODEL * 2;         // 12,582,912
    const size_t szW1 = (size_t)2 * NPROJ * DMODEL * 2;    // 10,297,344
    const size_t szXB = (size_t)8192 * CONVDIM * 2;        // 29,360,128
    const size_t szYb = (size_t)8192 * DINNER * 2;         // 25,165,824 (bf16 partial)
    const size_t szRa = szA1 + szW1 + szXB;                // 52,240,384
    const size_t szR  = (szRa > 2 * szYb) ? szRa : 2 * szYb;

    char* ws = (char*)d_ws;
    size_t off = 0;
    auto alloc = [&](size_t bytes) { char* p = ws + off; off += (bytes + 255) & ~(size_t)255; return p; };

    __hip_bfloat16* W2 = (__hip_bfloat16*)alloc(szW2);
    __hip_bfloat16* Z  = (__hip_bfloat16*)alloc(szZ);
    __hip_bfloat16* XH = (__hip_bfloat16*)alloc(szXH);
    float* BM = (float*)alloc(szBM);
    float* CM = (float*)alloc(szCM);
    float* DT = (float*)alloc(szDT);
    float* DA = (float*)alloc(szDA);
    char*  R  = (char*)alloc(szR);
    // region R: [A1 | W1 | XBC] (dead after conv)  overlaid later by  [Y0 | Y1] (bf16, scan output)
    __hip_bfloat16* A1  = (__hip_bfloat16*)R;
    __hip_bfloat16* W1  = (__hip_bfloat16*)(R + szA1);
    __hip_bfloat16* XBC = (__hip_bfloat16*)(R + szA1 + szW1);
    __hip_bfloat16* Y0  = (__hip_bfloat16*)R;
    __hip_bfloat16* Y1  = (__hip_bfloat16*)(R + szYb);

    if (off > ws_size) return;   // clean fail (absmax) instead of OOB crash — diagnostic

    // 1. weight converts
    int n1 = 2 * NPROJ * DMODEL;
    cvt_kernel<<<(n1 + 255) / 256, 256, 0, stream>>>(in_w, W1, n1);
    int n2 = 2 * DMODEL * DINNER;
    cvt_kernel<<<(n2 + 255) / 256, 256, 0, stream>>>(out_w, W2, n2);
    // 2. x -> bf16 (flipped copy for dir 1)
    int n3 = 2 * 4096 * DMODEL;
    prep_x_kernel<<<(n3 + 255) / 256, 256, 0, stream>>>(x, A1);

    // 3. in_proj GEMMs (per dir) with routing epilogue
    {
        dim3 grid((NPROJ + 63) / 64, 4096 / 64);
        for (int dir = 0; dir < 2; dir++) {
            gemm_bt<<<grid, 256, 0, stream>>>(A1 + (size_t)dir * 4096 * DMODEL,
                                              W1 + (size_t)dir * NPROJ * DMODEL,
                                              nullptr,
                                              Z   + (size_t)dir * 4096 * DINNER,
                                              XBC + (size_t)dir * 4096 * CONVDIM,
                                              DT  + (size_t)dir * 4096 * NH,
                                              DA  + (size_t)dir * 4096 * NH,
                                              dt_bias + dir * NH,
                                              A_log   + dir * NH,
                                              4096, NPROJ, DMODEL, 2);
        }
    }

    // 4. conv + silu
    conv_kernel<<<4 * (SEQ / 8), 256, 0, stream>>>(XBC, conv_w, conv_b, XH, BM, CM);

    // 5. barrier-free scan (Y0/Y1 overlay A1/W1/XBC — all dead now)
    scan_kernel<<<4 * NH * 2 * 4, 64, 0, stream>>>(XH, BM, CM, DT, DA, Y0, Y1);

    // 6. gating + RMSNorm (A2 == Z, in-place)
    gate_kernel<<<2 * 4096, 256, 0, stream>>>(Y0, Y1, XH, Z, Dp, norm_w, Z);

    // 7. out_proj GEMMs; dir0 overwrites, dir1 flip-adds (same stream -> ordered)
    {
        dim3 grid(DMODEL / 64, 4096 / 64);
        gemm_bt<<<grid, 256, 0, stream>>>(Z, W2, out,
                                          nullptr, nullptr, nullptr, nullptr, nullptr, nullptr,
                                          4096, DMODEL, DINNER, 0);
        gemm_bt<<<grid, 256, 0, stream>>>(Z + (size_t)4096 * DINNER,
                                          W2 + (size_t)DMODEL * DINNER,
                                          out,
                                          nullptr, nullptr, nullptr, nullptr, nullptr, nullptr,
                                          4096, DMODEL, DINNER, 1);
    }
}

// Round 4
// 1037.085 us; speedup vs baseline: 1.6695x; 1.5410x over previous
//
#include <hip/hip_runtime.h>
#include <hip/hip_bf16.h>

typedef __attribute__((ext_vector_type(8))) short short8;
typedef __attribute__((ext_vector_type(4))) float floatx4;

#define SEQ     2048
#define DMODEL  768
#define DINNER  1536
#define DSTATE  128
#define NH      24
#define CONVDIM 1792
#define NPROJ   3352   // 2*DINNER + 2*DSTATE + NH

// ---------------------------------------------------------------- converts
__global__ __launch_bounds__(256) void cvt_kernel(const float* __restrict__ src,
                                                  __hip_bfloat16* __restrict__ dst, int n) {
    int i = blockIdx.x * 256 + threadIdx.x;
    if (i < n) dst[i] = __float2bfloat16(src[i]);
}

// Build A1[dir][b*SEQ+t][k] = bf16(x[b][dir? SEQ-1-t : t][k])
__global__ __launch_bounds__(256) void prep_x_kernel(const float* __restrict__ x,
                                                     __hip_bfloat16* __restrict__ A1) {
    size_t idx = (size_t)blockIdx.x * 256 + threadIdx.x;
    const size_t total = (size_t)2 * 2 * SEQ * DMODEL;
    if (idx >= total) return;
    int k = (int)(idx % DMODEL);
    size_t m = idx / DMODEL;
    int dir = (int)(m >> 12);          // 4096 rows per dir
    int mm  = (int)(m & 4095);
    int b = mm >> 11, t = mm & 2047;
    int ts = dir ? (SEQ - 1 - t) : t;
    A1[idx] = __float2bfloat16(x[((size_t)(b * SEQ + ts)) * DMODEL + k]);
}

// ---------------------------------------------------------------- GEMM: C = A[M,K] @ Bw[N,K]^T
__global__ __launch_bounds__(256) void gemm_bt(const __hip_bfloat16* __restrict__ A,
                                               const __hip_bfloat16* __restrict__ Bw,
                                               float* __restrict__ C,
                                               __hip_bfloat16* __restrict__ Zb,
                                               __hip_bfloat16* __restrict__ Xb,
                                               float* __restrict__ DT,
                                               float* __restrict__ DA,
                                               const float* __restrict__ dtbias,
                                               const float* __restrict__ Alog,
                                               int M, int N, int K, int mode) {
    __shared__ __hip_bfloat16 As[64][40];   // pitch 40 -> 2-way bank alias only (free)
    __shared__ __hip_bfloat16 Bs[64][40];
    int tid = threadIdx.x;
    int m0 = blockIdx.y * 64, n0 = blockIdx.x * 64;
    int w = tid >> 6, lane = tid & 63;
    int q = lane >> 4, mm = lane & 15;
    int srow = tid >> 2, scol = (tid & 3) * 8;
    int ar = m0 + srow;                       // always < M (M multiple of 64)
    int br = n0 + srow; if (br > N - 1) br = N - 1;   // clamp (dup rows; cols skipped on store)

    floatx4 acc[4];
#pragma unroll
    for (int i = 0; i < 4; i++) acc[i] = (floatx4){0.f, 0.f, 0.f, 0.f};

    for (int k0 = 0; k0 < K; k0 += 32) {
        short8 av = *(const short8*)(A  + (size_t)ar * K + k0 + scol);
        short8 bv = *(const short8*)(Bw + (size_t)br * K + k0 + scol);
        *(short8*)(&As[srow][scol]) = av;
        *(short8*)(&Bs[srow][scol]) = bv;
        __syncthreads();
        short8 af = *(const short8*)(&As[w * 16 + mm][q * 8]);
#pragma unroll
        for (int cb = 0; cb < 4; cb++) {
            short8 bf = *(const short8*)(&Bs[cb * 16 + mm][q * 8]);
            acc[cb] = __builtin_amdgcn_mfma_f32_16x16x32_bf16(af, bf, acc[cb], 0, 0, 0);
        }
        __syncthreads();
    }

    int row = m0 + w * 16 + q * 4;
#pragma unroll
    for (int cb = 0; cb < 4; cb++) {
        int col = n0 + cb * 16 + mm;
        if (col >= N) continue;
#pragma unroll
        for (int r = 0; r < 4; r++) {
            int rr = row + r;
            float v = acc[cb][r];
            if (mode == 0) {
                C[(size_t)rr * N + col] = v;
            } else if (mode == 1) {
                int b = rr >> 11, t = rr & 2047;
                int orow = (b << 11) + (2047 - t);
                C[(size_t)orow * N + col] += v;
            } else {
                if (col < DINNER) {
                    Zb[(size_t)rr * DINNER + col] = __float2bfloat16(v);
                } else if (col < DINNER + CONVDIM) {
                    Xb[(size_t)rr * CONVDIM + (col - DINNER)] = __float2bfloat16(v);
                } else {
                    int hh = col - (DINNER + CONVDIM);
                    float raw = v + dtbias[hh];
                    float dtv = (raw > 20.f) ? raw : log1pf(__expf(raw));
                    float dAv = __expf(dtv * (-__expf(Alog[hh])));
                    DT[(size_t)rr * NH + hh] = dtv;
                    DA[(size_t)rr * NH + hh] = dAv;
                }
            }
        }
    }
}

// ---------------------------------------------------------------- conv (depthwise K=4) + silu
__global__ __launch_bounds__(256) void conv_kernel(const __hip_bfloat16* __restrict__ Xb,
                                                   const float* __restrict__ conv_w,
                                                   const float* __restrict__ conv_b,
                                                   __hip_bfloat16* __restrict__ xh,
                                                   float* __restrict__ Bm,
                                                   float* __restrict__ Cm) {
    int db  = blockIdx.x >> 8;            // 4 of these
    int dir = db >> 1;
    int t0  = (blockIdx.x & 255) * 8;
    for (int tt = 0; tt < 8; tt++) {
        int t = t0 + tt;
        for (int c = threadIdx.x; c < CONVDIM; c += 256) {
            float acc = conv_b[dir * CONVDIM + c];
#pragma unroll
            for (int k = 0; k < 4; k++) {
                int ts = t - 3 + k;
                float v = (ts >= 0) ? __bfloat162float(Xb[((size_t)db * SEQ + ts) * CONVDIM + c]) : 0.f;
                acc += v * conv_w[((size_t)dir * CONVDIM + c) * 4 + k];
            }
            float sv = acc / (1.f + __expf(-acc));   // silu
            if (c < DINNER)
                xh[((size_t)db * SEQ + t) * DINNER + c] = __float2bfloat16(sv);
            else if (c < DINNER + DSTATE)
                Bm[((size_t)db * SEQ + t) * DSTATE + (c - DINNER)] = sv;
            else
                Cm[((size_t)db * SEQ + t) * DSTATE + (c - DINNER - DSTATE)] = sv;
        }
    }
}

// ---------------------------------------------------------------- sequential scan, barrier-free, pipelined
// 1 wave per block. blk = ((db*NH + hh)*32 + pg).  pg = p-group of 2.
// lane l: p = pg*2 + (l>>5); owns 4 states n = (l&31)*4 .. +4  (full 128 n per wave).
// y reduced over the 32 lanes of each half-wave via shfl_xor(1,2,4,8,16).
// Double-buffered 4-step groups: prefetch group g+1 before computing group g.
__global__ __launch_bounds__(64) void scan_kernel(const __hip_bfloat16* __restrict__ xh,
                                                  const float* __restrict__ Bm,
                                                  const float* __restrict__ Cm,
                                                  const float* __restrict__ dtb,
                                                  const float* __restrict__ dAb,
                                                  __hip_bfloat16* __restrict__ Yb) {
    int blk = blockIdx.x;
    int pg = blk & 31;
    int t1 = blk >> 5;
    int hh = t1 % NH, db = t1 / NH;
    int l = threadIdx.x;
    int p  = pg * 2 + (l >> 5);
    int nb = (l & 31) * 4;

    const float* Bp = Bm + (size_t)db * SEQ * DSTATE + nb;
    const float* Cp = Cm + (size_t)db * SEQ * DSTATE + nb;
    const __hip_bfloat16* xp = xh + (size_t)db * SEQ * DINNER + hh * 64 + p;
    const float* dtp = dtb + (size_t)db * SEQ * NH + hh;
    const float* dAp = dAb + (size_t)db * SEQ * NH + hh;
    __hip_bfloat16* yp = Yb + (size_t)db * SEQ * DINNER + hh * 64 + p;

    float h0 = 0.f, h1 = 0.f, h2 = 0.f, h3 = 0.f;

    float4 b0[4], c0[4], b1[4], c1[4];
    float x0[4], d0[4], a0[4], x1[4], d1[4], a1[4];

#define LOADG(BUF, T0)                                                              \
    {                                                                               \
        _Pragma("unroll")                                                           \
        for (int u = 0; u < 4; u++) {                                               \
            int tt = (T0) + u; if (tt > SEQ - 1) tt = SEQ - 1;                      \
            b##BUF[u] = *(const float4*)(Bp + (size_t)tt * DSTATE);                 \
            c##BUF[u] = *(const float4*)(Cp + (size_t)tt * DSTATE);                 \
            x##BUF[u] = __bfloat162float(xp[(size_t)tt * DINNER]);                  \
            d##BUF[u] = dtp[(size_t)tt * NH];                                       \
            a##BUF[u] = dAp[(size_t)tt * NH];                                       \
        }                                                                           \
    }

#define COMPG(BUF, T0)                                                              \
    {                                                                               \
        _Pragma("unroll")                                                           \
        for (int u = 0; u < 4; u++) {                                               \
            float dtx = d##BUF[u] * x##BUF[u];                                      \
            float dAv = a##BUF[u];                                                  \
            float4 bv = b##BUF[u], cv = c##BUF[u];                                  \
            h0 = fmaf(h0, dAv, dtx * bv.x);                                         \
            h1 = fmaf(h1, dAv, dtx * bv.y);                                         \
            h2 = fmaf(h2, dAv, dtx * bv.z);                                         \
            h3 = fmaf(h3, dAv, dtx * bv.w);                                         \
            float yac = h0 * cv.x + h1 * cv.y + h2 * cv.z + h3 * cv.w;              \
            yac += __shfl_xor(yac, 1);                                              \
            yac += __shfl_xor(yac, 2);                                              \
            yac += __shfl_xor(yac, 4);                                              \
            yac += __shfl_xor(yac, 8);                                              \
            yac += __shfl_xor(yac, 16);                                             \
            if ((l & 31) == 0) yp[(size_t)((T0) + u) * DINNER] = __float2bfloat16(yac); \
        }                                                                           \
    }

    LOADG(0, 0)
    for (int tg = 0; tg < SEQ; tg += 8) {
        LOADG(1, tg + 4)
        COMPG(0, tg)
        LOADG(0, tg + 8)
        COMPG(1, tg + 4)
    }
#undef LOADG
#undef COMPG
}

// ---------------------------------------------------------------- gating + RMSNorm -> bf16 A2 (in-place over Z)
__global__ __launch_bounds__(256) void gate_kernel(const __hip_bfloat16* __restrict__ Yb,
                                                   const __hip_bfloat16* __restrict__ xh,
                                                   const __hip_bfloat16* __restrict__ Zb,
                                                   const float* __restrict__ Dp,
                                                   const float* __restrict__ norm_w,
                                                   __hip_bfloat16* __restrict__ A2) {
    int row = blockIdx.x;           // db*SEQ + t, 0..8191
    int db = row >> 11;
    int dir = db >> 1;
    const __hip_bfloat16* yr = Yb + (size_t)row * DINNER;
    const __hip_bfloat16* xr = xh + (size_t)row * DINNER;
    const __hip_bfloat16* zr = Zb + (size_t)row * DINNER;

    float vals[6];
    float ss = 0.f;
#pragma unroll
    for (int i = 0; i < 6; i++) {
        int c = threadIdx.x + i * 256;
        float v = __bfloat162float(yr[c]) + Dp[dir * NH + (c >> 6)] * __bfloat162float(xr[c]);
        float z = __bfloat162float(zr[c]);
        v *= z / (1.f + __expf(-z));
        vals[i] = v;
        ss += v * v;
    }
#pragma unroll
    for (int off = 32; off; off >>= 1) ss += __shfl_down(ss, off);
    __shared__ float ls[4];
    if ((threadIdx.x & 63) == 0) ls[threadIdx.x >> 6] = ss;
    __syncthreads();
    float tot = ls[0] + ls[1] + ls[2] + ls[3];
    float scale = rsqrtf(tot / (float)DINNER + 1e-5f);
#pragma unroll
    for (int i = 0; i < 6; i++) {
        int c = threadIdx.x + i * 256;
        A2[(size_t)row * DINNER + c] = __float2bfloat16(vals[i] * scale * norm_w[dir * DINNER + c]);
    }
}

// ---------------------------------------------------------------- launch
extern "C" void kernel_launch(void* const* d_in, const int* in_sizes, int n_in,
                              void* d_out, int out_size, void* d_ws, size_t ws_size,
                              hipStream_t stream) {
    const float* x        = (const float*)d_in[0];
    const float* in_w     = (const float*)d_in[1];
    const float* conv_w   = (const float*)d_in[2];
    const float* conv_b   = (const float*)d_in[3];
    const float* dt_bias  = (const float*)d_in[4];
    const float* A_log    = (const float*)d_in[5];
    const float* Dp       = (const float*)d_in[6];
    const float* norm_w   = (const float*)d_in[7];
    const float* out_w    = (const float*)d_in[8];
    float* out = (float*)d_out;

    // ---- workspace layout (aliased, ~117 MB total) ----
    const size_t szW2 = (size_t)2 * DMODEL * DINNER * 2;   //  4,718,592
    const size_t szZ  = (size_t)8192 * DINNER * 2;         // 25,165,824 (also A2, in-place)
    const size_t szXH = (size_t)8192 * DINNER * 2;         // 25,165,824
    const size_t szBM = (size_t)8192 * DSTATE * 4;         //  4,194,304
    const size_t szCM = szBM;
    const size_t szDT = (size_t)8192 * NH * 4;             //    786,432
    const size_t szDA = szDT;
    const size_t szA1 = (size_t)8192 * DMODEL * 2;         // 12,582,912
    const size_t szW1 = (size_t)2 * NPROJ * DMODEL * 2;    // 10,297,344
    const size_t szXB = (size_t)8192 * CONVDIM * 2;        // 29,360,128
    const size_t szYb = (size_t)8192 * DINNER * 2;         // 25,165,824 (bf16)
    const size_t szRa = szA1 + szW1 + szXB;                // 52,240,384
    const size_t szR  = (szRa > szYb) ? szRa : szYb;

    char* ws = (char*)d_ws;
    size_t off = 0;
    auto alloc = [&](size_t bytes) { char* p = ws + off; off += (bytes + 255) & ~(size_t)255; return p; };

    __hip_bfloat16* W2 = (__hip_bfloat16*)alloc(szW2);
    __hip_bfloat16* Z  = (__hip_bfloat16*)alloc(szZ);
    __hip_bfloat16* XH = (__hip_bfloat16*)alloc(szXH);
    float* BM = (float*)alloc(szBM);
    float* CM = (float*)alloc(szCM);
    float* DT = (float*)alloc(szDT);
    float* DA = (float*)alloc(szDA);
    char*  R  = (char*)alloc(szR);
    // region R: [A1 | W1 | XBC] (dead after conv)  overlaid later by  Y (bf16, scan output)
    __hip_bfloat16* A1  = (__hip_bfloat16*)R;
    __hip_bfloat16* W1  = (__hip_bfloat16*)(R + szA1);
    __hip_bfloat16* XBC = (__hip_bfloat16*)(R + szA1 + szW1);
    __hip_bfloat16* Yb  = (__hip_bfloat16*)R;

    if (off > ws_size) return;   // clean fail (absmax) instead of OOB crash — diagnostic

    // 1. weight converts
    int n1 = 2 * NPROJ * DMODEL;
    cvt_kernel<<<(n1 + 255) / 256, 256, 0, stream>>>(in_w, W1, n1);
    int n2 = 2 * DMODEL * DINNER;
    cvt_kernel<<<(n2 + 255) / 256, 256, 0, stream>>>(out_w, W2, n2);
    // 2. x -> bf16 (flipped copy for dir 1)
    int n3 = 2 * 4096 * DMODEL;
    prep_x_kernel<<<(n3 + 255) / 256, 256, 0, stream>>>(x, A1);

    // 3. in_proj GEMMs (per dir) with routing epilogue
    {
        dim3 grid((NPROJ + 63) / 64, 4096 / 64);
        for (int dir = 0; dir < 2; dir++) {
            gemm_bt<<<grid, 256, 0, stream>>>(A1 + (size_t)dir * 4096 * DMODEL,
                                              W1 + (size_t)dir * NPROJ * DMODEL,
                                              nullptr,
                                              Z   + (size_t)dir * 4096 * DINNER,
                                              XBC + (size_t)dir * 4096 * CONVDIM,
                                              DT  + (size_t)dir * 4096 * NH,
                                              DA  + (size_t)dir * 4096 * NH,
                                              dt_bias + dir * NH,
                                              A_log   + dir * NH,
                                              4096, NPROJ, DMODEL, 2);
        }
    }

    // 4. conv + silu
    conv_kernel<<<4 * (SEQ / 8), 256, 0, stream>>>(XBC, conv_w, conv_b, XH, BM, CM);

    // 5. pipelined barrier-free scan (Yb overlays A1/W1/XBC — all dead now)
    scan_kernel<<<4 * NH * 32, 64, 0, stream>>>(XH, BM, CM, DT, DA, Yb);

    // 6. gating + RMSNorm (A2 == Z, in-place)
    gate_kernel<<<2 * 4096, 256, 0, stream>>>(Yb, XH, Z, Dp, norm_w, Z);

    // 7. out_proj GEMMs; dir0 overwrites, dir1 flip-adds (same stream -> ordered)
    {
        dim3 grid(DMODEL / 64, 4096 / 64);
        gemm_bt<<<grid, 256, 0, stream>>>(Z, W2, out,
                                          nullptr, nullptr, nullptr, nullptr, nullptr, nullptr,
                                          4096, DMODEL, DINNER, 0);
        gemm_bt<<<grid, 256, 0, stream>>>(Z + (size_t)4096 * DINNER,
                                          W2 + (size_t)DMODEL * DINNER,
                                          out,
                                          nullptr, nullptr, nullptr, nullptr, nullptr, nullptr,
                                          4096, DMODEL, DINNER, 1);
    }
}

// Round 6
// 505.692 us; speedup vs baseline: 3.4239x; 2.0508x over previous
//
#include <hip/hip_runtime.h>
#include <hip/hip_bf16.h>

typedef __attribute__((ext_vector_type(8))) short short8;
typedef __attribute__((ext_vector_type(4))) short bfx4;
typedef __attribute__((ext_vector_type(4))) float floatx4;

#define SEQ     2048
#define DMODEL  768
#define DINNER  1536
#define DSTATE  128
#define NH      24
#define CONVDIM 1792
#define NPROJ   3352   // 2*DINNER + 2*DSTATE + NH
#define QCH     64     // SSD chunk length
#define NCH     (SEQ / QCH)   // 32 chunks

__device__ inline float bf2f(short s) {
    return __uint_as_float(((unsigned)(unsigned short)s) << 16);
}
__device__ inline short f2bf(float f) {
    __hip_bfloat16 h = __float2bfloat16(f);
    return *reinterpret_cast<short*>(&h);
}

// ---------------------------------------------------------------- converts
__global__ __launch_bounds__(256) void cvt_kernel(const float* __restrict__ src,
                                                  __hip_bfloat16* __restrict__ dst, int n) {
    int i = blockIdx.x * 256 + threadIdx.x;
    if (i < n) dst[i] = __float2bfloat16(src[i]);
}

__global__ __launch_bounds__(256) void prep_x_kernel(const float* __restrict__ x,
                                                     __hip_bfloat16* __restrict__ A1) {
    size_t idx = (size_t)blockIdx.x * 256 + threadIdx.x;
    const size_t total = (size_t)2 * 2 * SEQ * DMODEL;
    if (idx >= total) return;
    int k = (int)(idx % DMODEL);
    size_t m = idx / DMODEL;
    int dir = (int)(m >> 12);
    int mm  = (int)(m & 4095);
    int b = mm >> 11, t = mm & 2047;
    int ts = dir ? (SEQ - 1 - t) : t;
    A1[idx] = __float2bfloat16(x[((size_t)(b * SEQ + ts)) * DMODEL + k]);
}

// ---------------------------------------------------------------- GEMM: C = A[M,K] @ Bw[N,K]^T
// mode 0: fp32 store. mode 1: C[flip(row)] += v. mode 2: in_proj routing (Z, XBC bf16; DT, LA fp32)
__global__ __launch_bounds__(256) void gemm_bt(const __hip_bfloat16* __restrict__ A,
                                               const __hip_bfloat16* __restrict__ Bw,
                                               float* __restrict__ C,
                                               __hip_bfloat16* __restrict__ Zb,
                                               __hip_bfloat16* __restrict__ Xb,
                                               float* __restrict__ DT,
                                               float* __restrict__ LA,
                                               const float* __restrict__ dtbias,
                                               const float* __restrict__ Alog,
                                               int M, int N, int K, int mode) {
    __shared__ __hip_bfloat16 As[64][40];
    __shared__ __hip_bfloat16 Bs[64][40];
    int tid = threadIdx.x;
    int m0 = blockIdx.y * 64, n0 = blockIdx.x * 64;
    int w = tid >> 6, lane = tid & 63;
    int q = lane >> 4, mm = lane & 15;
    int srow = tid >> 2, scol = (tid & 3) * 8;
    int ar = m0 + srow;
    int br = n0 + srow; if (br > N - 1) br = N - 1;

    floatx4 acc[4];
#pragma unroll
    for (int i = 0; i < 4; i++) acc[i] = (floatx4){0.f, 0.f, 0.f, 0.f};

    for (int k0 = 0; k0 < K; k0 += 32) {
        short8 av = *(const short8*)(A  + (size_t)ar * K + k0 + scol);
        short8 bv = *(const short8*)(Bw + (size_t)br * K + k0 + scol);
        *(short8*)(&As[srow][scol]) = av;
        *(short8*)(&Bs[srow][scol]) = bv;
        __syncthreads();
        short8 af = *(const short8*)(&As[w * 16 + mm][q * 8]);
#pragma unroll
        for (int cb = 0; cb < 4; cb++) {
            short8 bf = *(const short8*)(&Bs[cb * 16 + mm][q * 8]);
            acc[cb] = __builtin_amdgcn_mfma_f32_16x16x32_bf16(af, bf, acc[cb], 0, 0, 0);
        }
        __syncthreads();
    }

    int row = m0 + w * 16 + q * 4;
#pragma unroll
    for (int cb = 0; cb < 4; cb++) {
        int col = n0 + cb * 16 + mm;
        if (col >= N) continue;
#pragma unroll
        for (int r = 0; r < 4; r++) {
            int rr = row + r;
            float v = acc[cb][r];
            if (mode == 0) {
                C[(size_t)rr * N + col] = v;
            } else if (mode == 1) {
                int b = rr >> 11, t = rr & 2047;
                int orow = (b << 11) + (2047 - t);
                C[(size_t)orow * N + col] += v;
            } else {
                if (col < DINNER) {
                    Zb[(size_t)rr * DINNER + col] = __float2bfloat16(v);
                } else if (col < DINNER + CONVDIM) {
                    Xb[(size_t)rr * CONVDIM + (col - DINNER)] = __float2bfloat16(v);
                } else {
                    int hh = col - (DINNER + CONVDIM);
                    float raw = v + dtbias[hh];
                    float dtv = (raw > 20.f) ? raw : log1pf(__expf(raw));
                    float Av  = -__expf(Alog[hh]);
                    DT[(size_t)rr * NH + hh] = dtv;
                    LA[(size_t)rr * NH + hh] = dtv * Av;    // log(dA), always <= 0
                }
            }
        }
    }
}

// ---------------------------------------------------------------- conv (depthwise K=4) + silu
__global__ __launch_bounds__(256) void conv_kernel(const __hip_bfloat16* __restrict__ Xb,
                                                   const float* __restrict__ conv_w,
                                                   const float* __restrict__ conv_b,
                                                   __hip_bfloat16* __restrict__ xh,
                                                   __hip_bfloat16* __restrict__ Bm,
                                                   __hip_bfloat16* __restrict__ Cm) {
    int db  = blockIdx.x >> 8;
    int dir = db >> 1;
    int t0  = (blockIdx.x & 255) * 8;
    for (int tt = 0; tt < 8; tt++) {
        int t = t0 + tt;
        for (int c = threadIdx.x; c < CONVDIM; c += 256) {
            float acc = conv_b[dir * CONVDIM + c];
#pragma unroll
            for (int k = 0; k < 4; k++) {
                int ts = t - 3 + k;
                float v = (ts >= 0) ? __bfloat162float(Xb[((size_t)db * SEQ + ts) * CONVDIM + c]) : 0.f;
                acc += v * conv_w[((size_t)dir * CONVDIM + c) * 4 + k];
            }
            float sv = acc / (1.f + __expf(-acc));
            if (c < DINNER)
                xh[((size_t)db * SEQ + t) * DINNER + c] = __float2bfloat16(sv);
            else if (c < DINNER + DSTATE)
                Bm[((size_t)db * SEQ + t) * DSTATE + (c - DINNER)] = __float2bfloat16(sv);
            else
                Cm[((size_t)db * SEQ + t) * DSTATE + (c - DINNER - DSTATE)] = __float2bfloat16(sv);
        }
    }
}

// ---------------------------------------------------------------- SSD pass 1
// per (db,hh,chunk): cum = prefix(la); S[p][n] = sum_s dt_s*exp(cumL-cum_s)*X[s][p]*B[s][n]
// blk = db*768 + hh*32 + ck
__global__ __launch_bounds__(256) void ssd1_kernel(const __hip_bfloat16* __restrict__ XH,
                                                   const __hip_bfloat16* __restrict__ BMh,
                                                   const float* __restrict__ DT,
                                                   const float* __restrict__ LA,
                                                   short* __restrict__ SS,
                                                   float* __restrict__ CUM) {
    int blk = blockIdx.x;
    int ck = blk & 31;
    int dbh = blk >> 5;               // db*24 + hh
    int hh = dbh % NH, db = dbh / NH;
    int base_row = db * SEQ + ck * QCH;

    __shared__ float cum_s[QCH], dt_s[QCH];
    __shared__ short Xt[64][72];      // X~^T : [p][s], scaled
    __shared__ short Bt[128][72];     // B^T  : [n][s]

    int tid = threadIdx.x;
    int lane = tid & 63, w = tid >> 6;
    int q = lane >> 4, mm = lane & 15;

    if (tid < QCH) {
        float la  = LA[(size_t)(base_row + tid) * NH + hh];
        float dtv = DT[(size_t)(base_row + tid) * NH + hh];
        float cs = la;
#pragma unroll
        for (int d = 1; d < 64; d <<= 1) {
            float u = __shfl_up(cs, d);
            if (tid >= d) cs += u;
        }
        cum_s[tid] = cs;
        dt_s[tid] = dtv;
        CUM[(size_t)dbh * SEQ + ck * QCH + tid] = cs;
    }
    __syncthreads();
    float cumL = cum_s[QCH - 1];

    // build Xt (scaled) : thread = (s2 pair, pb of 8 p)
    {
        int s2 = (tid & 31) * 2, pb = tid >> 5;
        float f0 = dt_s[s2]     * __expf(cumL - cum_s[s2]);
        float f1 = dt_s[s2 + 1] * __expf(cumL - cum_s[s2 + 1]);
        const short* r0 = (const short*)XH + (size_t)(base_row + s2) * DINNER + hh * 64 + pb * 8;
        const short* r1 = r0 + DINNER;
        short8 x0 = *(const short8*)r0;
        short8 x1 = *(const short8*)r1;
#pragma unroll
        for (int j = 0; j < 8; j++) {
            unsigned lo = (unsigned short)f2bf(f0 * bf2f(x0[j]));
            unsigned hi = (unsigned short)f2bf(f1 * bf2f(x1[j]));
            *(unsigned*)&Xt[pb * 8 + j][s2] = lo | (hi << 16);
        }
    }
    // build Bt : thread = (s2 pair, nb of 16 n)
    {
        int s2 = (tid & 31) * 2, nb = tid >> 5;
        const short* r0 = (const short*)BMh + (size_t)(base_row + s2) * DSTATE + nb * 16;
        const short* r1 = r0 + DSTATE;
        short8 b0a = *(const short8*)r0,  b0b = *(const short8*)(r0 + 8);
        short8 b1a = *(const short8*)r1,  b1b = *(const short8*)(r1 + 8);
#pragma unroll
        for (int j = 0; j < 8; j++) {
            *(unsigned*)&Bt[nb * 16 + j][s2] =
                (unsigned)(unsigned short)b0a[j] | ((unsigned)(unsigned short)b1a[j] << 16);
            *(unsigned*)&Bt[nb * 16 + 8 + j][s2] =
                (unsigned)(unsigned short)b0b[j] | ((unsigned)(unsigned short)b1b[j] << 16);
        }
    }
    __syncthreads();

    // MFMA: S[p][n], wave w owns p-rows [w*16, w*16+16), 8 col-blocks over n, K = 64 s
    floatx4 acc[8];
#pragma unroll
    for (int i = 0; i < 8; i++) acc[i] = (floatx4){0.f, 0.f, 0.f, 0.f};
#pragma unroll
    for (int kk = 0; kk < 2; kk++) {
        short8 a = *(const short8*)&Xt[w * 16 + mm][kk * 32 + q * 8];
#pragma unroll
        for (int cb = 0; cb < 8; cb++) {
            short8 b = *(const short8*)&Bt[cb * 16 + mm][kk * 32 + q * 8];
            acc[cb] = __builtin_amdgcn_mfma_f32_16x16x32_bf16(a, b, acc[cb], 0, 0, 0);
        }
    }
    short* Sp = SS + (size_t)blk * 8192;
#pragma unroll
    for (int cb = 0; cb < 8; cb++)
#pragma unroll
        for (int r = 0; r < 4; r++)
            Sp[(w * 16 + q * 4 + r) * DSTATE + cb * 16 + mm] = f2bf(acc[cb][r]);
}

// ---------------------------------------------------------------- SSD pass 2: inter-chunk scan
// 96 blocks (db*24+hh), 256 threads; h state fp32; Hprev[c] = state BEFORE chunk c
__global__ __launch_bounds__(256) void ssd2_kernel(const short* __restrict__ SS,
                                                   const float* __restrict__ CUM,
                                                   short* __restrict__ Hprev) {
    int dbh = blockIdx.x;
    int tid = threadIdx.x;
    size_t base = (size_t)dbh * NCH * 8192;
    float h[32];
#pragma unroll
    for (int k = 0; k < 32; k++) h[k] = 0.f;
    for (int c = 0; c < NCH; c++) {
        float W = __expf(CUM[(size_t)dbh * SEQ + c * QCH + QCH - 1]);
        size_t cb = base + (size_t)c * 8192;
#pragma unroll
        for (int k = 0; k < 32; k++) {
            int idx = k * 256 + tid;
            Hprev[cb + idx] = f2bf(h[k]);
            h[k] = h[k] * W + bf2f(SS[cb + idx]);
        }
    }
}

// ---------------------------------------------------------------- SSD pass 3
// per (db,hh,chunk): P = C@B^T; G = P * exp(cum_t-cum_s)*dt_s (s<=t);
// Y[t][p] = G@X + (exp(cum_t)*C) @ Hprev^T ; write bf16 Yb
__global__ __launch_bounds__(256) void ssd3_kernel(const __hip_bfloat16* __restrict__ XH,
                                                   const __hip_bfloat16* __restrict__ BMh,
                                                   const __hip_bfloat16* __restrict__ CMh,
                                                   const float* __restrict__ DT,
                                                   const float* __restrict__ CUM,
                                                   const short* __restrict__ Hprev,
                                                   __hip_bfloat16* __restrict__ Yb) {
    int blk = blockIdx.x;
    int ck = blk & 31;
    int dbh = blk >> 5;
    int hh = dbh % NH, db = dbh / NH;
    int base_row = db * SEQ + ck * QCH;

    __shared__ float cum_s[QCH], dt_s[QCH];
    __shared__ short Ct[64][136];     // w_t * C_t[n]
    __shared__ short G[64][72];       // [t][s]
    __shared__ short Xt[64][72];      // [p][s]

    int tid = threadIdx.x;
    int lane = tid & 63, w = tid >> 6;
    int q = lane >> 4, mm = lane & 15;

    if (tid < QCH) {
        cum_s[tid] = CUM[(size_t)dbh * SEQ + ck * QCH + tid];
        dt_s[tid]  = DT[(size_t)(base_row + tid) * NH + hh];
    }

    // MFMA1 (global frags, no LDS dependency): P[t][s] = sum_n C[t][n] B[s][n]
    const short* Cg = (const short*)CMh + (size_t)base_row * DSTATE;
    const short* Bg = (const short*)BMh + (size_t)base_row * DSTATE;
    floatx4 P[4];
#pragma unroll
    for (int i = 0; i < 4; i++) P[i] = (floatx4){0.f, 0.f, 0.f, 0.f};
#pragma unroll
    for (int kk = 0; kk < 4; kk++) {
        short8 a = *(const short8*)(Cg + (size_t)(w * 16 + mm) * DSTATE + kk * 32 + q * 8);
#pragma unroll
        for (int cb = 0; cb < 4; cb++) {
            short8 b = *(const short8*)(Bg + (size_t)(cb * 16 + mm) * DSTATE + kk * 32 + q * 8);
            P[cb] = __builtin_amdgcn_mfma_f32_16x16x32_bf16(a, b, P[cb], 0, 0, 0);
        }
    }
    __syncthreads();   // cum_s, dt_s visible

    // build Ct = exp(cum_t) * C_t  (thread: t = tid&63, nb4 = tid>>6 covers 32 n)
    {
        int t = tid & 63, nb4 = tid >> 6;
        float wt = __expf(cum_s[t]);
        const short* src = Cg + (size_t)t * DSTATE + nb4 * 32;
#pragma unroll
        for (int u = 0; u < 2; u++) {
            short8 v = *(const short8*)(src + u * 16);
            short8 v2 = *(const short8*)(src + u * 16 + 8);
#pragma unroll
            for (int j = 0; j < 4; j++) {
                unsigned lo = (unsigned short)f2bf(wt * bf2f(v[2 * j]));
                unsigned hi = (unsigned short)f2bf(wt * bf2f(v[2 * j + 1]));
                *(unsigned*)&Ct[t][nb4 * 32 + u * 16 + 2 * j] = lo | (hi << 16);
                lo = (unsigned short)f2bf(wt * bf2f(v2[2 * j]));
                hi = (unsigned short)f2bf(wt * bf2f(v2[2 * j + 1]));
                *(unsigned*)&Ct[t][nb4 * 32 + u * 16 + 8 + 2 * j] = lo | (hi << 16);
            }
        }
    }
    // build Xt (unscaled)
    {
        int s2 = (tid & 31) * 2, pb = tid >> 5;
        const short* r0 = (const short*)XH + (size_t)(base_row + s2) * DINNER + hh * 64 + pb * 8;
        const short* r1 = r0 + DINNER;
        short8 x0 = *(const short8*)r0;
        short8 x1 = *(const short8*)r1;
#pragma unroll
        for (int j = 0; j < 8; j++) {
            *(unsigned*)&Xt[pb * 8 + j][s2] =
                (unsigned)(unsigned short)x0[j] | ((unsigned)(unsigned short)x1[j] << 16);
        }
    }
    // scale P -> G (each wave writes its own rows [w*16, w*16+16))
#pragma unroll
    for (int cb = 0; cb < 4; cb++) {
#pragma unroll
        for (int r = 0; r < 4; r++) {
            int t = w * 16 + q * 4 + r;
            int s = cb * 16 + mm;
            float g = (s <= t) ? P[cb][r] * __expf(cum_s[t] - cum_s[s]) * dt_s[s] : 0.f;
            G[t][s] = f2bf(g);
        }
    }
    __syncthreads();

    // MFMA2: Y += G @ X   (K = 64 s)
    floatx4 Y[4];
#pragma unroll
    for (int i = 0; i < 4; i++) Y[i] = (floatx4){0.f, 0.f, 0.f, 0.f};
#pragma unroll
    for (int kk = 0; kk < 2; kk++) {
        short8 a = *(const short8*)&G[w * 16 + mm][kk * 32 + q * 8];
#pragma unroll
        for (int cb = 0; cb < 4; cb++) {
            short8 b = *(const short8*)&Xt[cb * 16 + mm][kk * 32 + q * 8];
            Y[cb] = __builtin_amdgcn_mfma_f32_16x16x32_bf16(a, b, Y[cb], 0, 0, 0);
        }
    }
    // MFMA3: Y += Ct @ Hprev^T   (K = 128 n)
    const short* Hc = Hprev + (size_t)blk * 8192;
#pragma unroll
    for (int kk = 0; kk < 4; kk++) {
        short8 a = *(const short8*)&Ct[w * 16 + mm][kk * 32 + q * 8];
#pragma unroll
        for (int cb = 0; cb < 4; cb++) {
            short8 b = *(const short8*)(Hc + (size_t)(cb * 16 + mm) * DSTATE + kk * 32 + q * 8);
            Y[cb] = __builtin_amdgcn_mfma_f32_16x16x32_bf16(a, b, Y[cb], 0, 0, 0);
        }
    }
    // epilogue
#pragma unroll
    for (int cb = 0; cb < 4; cb++)
#pragma unroll
        for (int r = 0; r < 4; r++)
            Yb[(size_t)(base_row + w * 16 + q * 4 + r) * DINNER + hh * 64 + cb * 16 + mm] =
                __float2bfloat16(Y[cb][r]);
}

// ---------------------------------------------------------------- fallback scan (bf16 B/C, la)
__global__ __launch_bounds__(64) void scan_kernel(const __hip_bfloat16* __restrict__ xh,
                                                  const __hip_bfloat16* __restrict__ Bm,
                                                  const __hip_bfloat16* __restrict__ Cm,
                                                  const float* __restrict__ dtb,
                                                  const float* __restrict__ lab,
                                                  __hip_bfloat16* __restrict__ Yb) {
    int blk = blockIdx.x;
    int pg = blk & 31;
    int t1 = blk >> 5;
    int hh = t1 % NH, db = t1 / NH;
    int l = threadIdx.x;
    int p  = pg * 2 + (l >> 5);
    int nb = (l & 31) * 4;

    const short* Bp = (const short*)Bm + (size_t)db * SEQ * DSTATE + nb;
    const short* Cp = (const short*)Cm + (size_t)db * SEQ * DSTATE + nb;
    const __hip_bfloat16* xp = xh + (size_t)db * SEQ * DINNER + hh * 64 + p;
    const float* dtp = dtb + (size_t)db * SEQ * NH + hh;
    const float* lap = lab + (size_t)db * SEQ * NH + hh;
    __hip_bfloat16* yp = Yb + (size_t)db * SEQ * DINNER + hh * 64 + p;

    float h0 = 0.f, h1 = 0.f, h2 = 0.f, h3 = 0.f;
    bfx4 b0[4], c0[4], b1[4], c1[4];
    float x0[4], d0[4], a0[4], x1[4], d1[4], a1[4];

#define LOADG(BUF, T0)                                                              \
    {                                                                               \
        _Pragma("unroll")                                                           \
        for (int u = 0; u < 4; u++) {                                               \
            int tt = (T0) + u; if (tt > SEQ - 1) tt = SEQ - 1;                      \
            b##BUF[u] = *(const bfx4*)(Bp + (size_t)tt * DSTATE);                   \
            c##BUF[u] = *(const bfx4*)(Cp + (size_t)tt * DSTATE);                   \
            x##BUF[u] = __bfloat162float(xp[(size_t)tt * DINNER]);                  \
            d##BUF[u] = dtp[(size_t)tt * NH];                                       \
            a##BUF[u] = lap[(size_t)tt * NH];                                       \
        }                                                                           \
    }
#define COMPG(BUF, T0)                                                              \
    {                                                                               \
        _Pragma("unroll")                                                           \
        for (int u = 0; u < 4; u++) {                                               \
            float dtx = d##BUF[u] * x##BUF[u];                                      \
            float dAv = __expf(a##BUF[u]);                                          \
            float yac;                                                              \
            h0 = fmaf(h0, dAv, dtx * bf2f(b##BUF[u][0]));                           \
            h1 = fmaf(h1, dAv, dtx * bf2f(b##BUF[u][1]));                           \
            h2 = fmaf(h2, dAv, dtx * bf2f(b##BUF[u][2]));                           \
            h3 = fmaf(h3, dAv, dtx * bf2f(b##BUF[u][3]));                           \
            yac = h0 * bf2f(c##BUF[u][0]) + h1 * bf2f(c##BUF[u][1])                 \
                + h2 * bf2f(c##BUF[u][2]) + h3 * bf2f(c##BUF[u][3]);                \
            yac += __shfl_xor(yac, 1);                                              \
            yac += __shfl_xor(yac, 2);                                              \
            yac += __shfl_xor(yac, 4);                                              \
            yac += __shfl_xor(yac, 8);                                              \
            yac += __shfl_xor(yac, 16);                                             \
            if ((l & 31) == 0) yp[(size_t)((T0) + u) * DINNER] = __float2bfloat16(yac); \
        }                                                                           \
    }
    LOADG(0, 0)
    for (int tg = 0; tg < SEQ; tg += 8) {
        LOADG(1, tg + 4)
        COMPG(0, tg)
        LOADG(0, tg + 8)
        COMPG(1, tg + 4)
    }
#undef LOADG
#undef COMPG
}

// ---------------------------------------------------------------- gating + RMSNorm -> bf16 A2 (in-place over Z)
__global__ __launch_bounds__(256) void gate_kernel(const __hip_bfloat16* __restrict__ Yb,
                                                   const __hip_bfloat16* __restrict__ xh,
                                                   const __hip_bfloat16* __restrict__ Zb,
                                                   const float* __restrict__ Dp,
                                                   const float* __restrict__ norm_w,
                                                   __hip_bfloat16* __restrict__ A2) {
    int row = blockIdx.x;
    int db = row >> 11;
    int dir = db >> 1;
    const __hip_bfloat16* yr = Yb + (size_t)row * DINNER;
    const __hip_bfloat16* xr = xh + (size_t)row * DINNER;
    const __hip_bfloat16* zr = Zb + (size_t)row * DINNER;

    float vals[6];
    float ss = 0.f;
#pragma unroll
    for (int i = 0; i < 6; i++) {
        int c = threadIdx.x + i * 256;
        float v = __bfloat162float(yr[c]) + Dp[dir * NH + (c >> 6)] * __bfloat162float(xr[c]);
        float z = __bfloat162float(zr[c]);
        v *= z / (1.f + __expf(-z));
        vals[i] = v;
        ss += v * v;
    }
#pragma unroll
    for (int off = 32; off; off >>= 1) ss += __shfl_down(ss, off);
    __shared__ float ls[4];
    if ((threadIdx.x & 63) == 0) ls[threadIdx.x >> 6] = ss;
    __syncthreads();
    float tot = ls[0] + ls[1] + ls[2] + ls[3];
    float scale = rsqrtf(tot / (float)DINNER + 1e-5f);
#pragma unroll
    for (int i = 0; i < 6; i++) {
        int c = threadIdx.x + i * 256;
        A2[(size_t)row * DINNER + c] = __float2bfloat16(vals[i] * scale * norm_w[dir * DINNER + c]);
    }
}

// ---------------------------------------------------------------- launch
extern "C" void kernel_launch(void* const* d_in, const int* in_sizes, int n_in,
                              void* d_out, int out_size, void* d_ws, size_t ws_size,
                              hipStream_t stream) {
    const float* x        = (const float*)d_in[0];
    const float* in_w     = (const float*)d_in[1];
    const float* conv_w   = (const float*)d_in[2];
    const float* conv_b   = (const float*)d_in[3];
    const float* dt_bias  = (const float*)d_in[4];
    const float* A_log    = (const float*)d_in[5];
    const float* Dp       = (const float*)d_in[6];
    const float* norm_w   = (const float*)d_in[7];
    const float* out_w    = (const float*)d_in[8];
    float* out = (float*)d_out;

    const size_t szW2 = (size_t)2 * DMODEL * DINNER * 2;
    const size_t szZ  = (size_t)8192 * DINNER * 2;
    const size_t szXH = (size_t)8192 * DINNER * 2;
    const size_t szBM = (size_t)8192 * DSTATE * 2;     // bf16 now
    const size_t szCM = szBM;
    const size_t szDT = (size_t)8192 * NH * 4;
    const size_t szLA = szDT;
    const size_t szA1 = (size_t)8192 * DMODEL * 2;
    const size_t szW1 = (size_t)2 * NPROJ * DMODEL * 2;
    const size_t szXB = (size_t)8192 * CONVDIM * 2;
    const size_t szYb = (size_t)8192 * DINNER * 2;
    const size_t szSS = (size_t)96 * NCH * 8192 * 2;   // 50.3 MB
    const size_t szRa = szA1 + szW1 + szXB;            // 52.2 MB
    size_t szR = szRa;
    if (szR < szYb) szR = szYb;
    if (szR < szSS) szR = szSS;
    const size_t szHp = szSS;
    const size_t szCU = (size_t)96 * SEQ * 4;

    char* ws = (char*)d_ws;
    size_t off = 0;
    auto alloc = [&](size_t bytes) { char* p = ws + off; off += (bytes + 255) & ~(size_t)255; return p; };

    __hip_bfloat16* W2 = (__hip_bfloat16*)alloc(szW2);
    __hip_bfloat16* Z  = (__hip_bfloat16*)alloc(szZ);
    __hip_bfloat16* XH = (__hip_bfloat16*)alloc(szXH);
    __hip_bfloat16* BM = (__hip_bfloat16*)alloc(szBM);
    __hip_bfloat16* CM = (__hip_bfloat16*)alloc(szCM);
    float* DT = (float*)alloc(szDT);
    float* LA = (float*)alloc(szLA);
    char*  R  = (char*)alloc(szR);
    size_t off_common = off;
    // region R timeline: [A1|W1|XBC] -> SS (ssd1 out) -> Yb (ssd3 out, overlays dead SS)
    __hip_bfloat16* A1  = (__hip_bfloat16*)R;
    __hip_bfloat16* W1  = (__hip_bfloat16*)(R + szA1);
    __hip_bfloat16* XBC = (__hip_bfloat16*)(R + szA1 + szW1);
    short* SS = (short*)R;
    __hip_bfloat16* Yb = (__hip_bfloat16*)R;

    short* Hp = (short*)alloc(szHp);
    float* CU = (float*)alloc(szCU);
    bool use_ssd = (off <= ws_size);
    if (!use_ssd && off_common > ws_size) return;   // even fallback doesn't fit

    // 1. weight converts
    int n1 = 2 * NPROJ * DMODEL;
    cvt_kernel<<<(n1 + 255) / 256, 256, 0, stream>>>(in_w, W1, n1);
    int n2 = 2 * DMODEL * DINNER;
    cvt_kernel<<<(n2 + 255) / 256, 256, 0, stream>>>(out_w, W2, n2);
    // 2. x -> bf16 (flipped copy for dir 1)
    int n3 = 2 * 4096 * DMODEL;
    prep_x_kernel<<<(n3 + 255) / 256, 256, 0, stream>>>(x, A1);

    // 3. in_proj GEMMs with routing epilogue
    {
        dim3 grid((NPROJ + 63) / 64, 4096 / 64);
        for (int dir = 0; dir < 2; dir++) {
            gemm_bt<<<grid, 256, 0, stream>>>(A1 + (size_t)dir * 4096 * DMODEL,
                                              W1 + (size_t)dir * NPROJ * DMODEL,
                                              nullptr,
                                              Z   + (size_t)dir * 4096 * DINNER,
                                              XBC + (size_t)dir * 4096 * CONVDIM,
                                              DT  + (size_t)dir * 4096 * NH,
                                              LA  + (size_t)dir * 4096 * NH,
                                              dt_bias + dir * NH,
                                              A_log   + dir * NH,
                                              4096, NPROJ, DMODEL, 2);
        }
    }

    // 4. conv + silu (bf16 B/C out)
    conv_kernel<<<4 * (SEQ / 8), 256, 0, stream>>>(XBC, conv_w, conv_b, XH, BM, CM);

    if (use_ssd) {
        // 5. SSD chunked scan (XBC/A1/W1 dead -> SS lives in R; then Yb overlays SS)
        ssd1_kernel<<<4 * NH * NCH, 256, 0, stream>>>(XH, BM, DT, LA, SS, CU);
        ssd2_kernel<<<4 * NH, 256, 0, stream>>>(SS, CU, Hp);
        ssd3_kernel<<<4 * NH * NCH, 256, 0, stream>>>(XH, BM, CM, DT, CU, Hp, Yb);
    } else {
        scan_kernel<<<4 * NH * 32, 64, 0, stream>>>(XH, BM, CM, DT, LA, Yb);
    }

    // 6. gating + RMSNorm (A2 == Z, in-place)
    gate_kernel<<<2 * 4096, 256, 0, stream>>>(Yb, XH, Z, Dp, norm_w, Z);

    // 7. out_proj GEMMs; dir0 overwrites, dir1 flip-adds
    {
        dim3 grid(DMODEL / 64, 4096 / 64);
        gemm_bt<<<grid, 256, 0, stream>>>(Z, W2, out,
                                          nullptr, nullptr, nullptr, nullptr, nullptr, nullptr,
                                          4096, DMODEL, DINNER, 0);
        gemm_bt<<<grid, 256, 0, stream>>>(Z + (size_t)4096 * DINNER,
                                          W2 + (size_t)DMODEL * DINNER,
                                          out,
                                          nullptr, nullptr, nullptr, nullptr, nullptr, nullptr,
                                          4096, DMODEL, DINNER, 1);
    }
}

// Round 7
// 503.468 us; speedup vs baseline: 3.4391x; 1.0044x over previous
//
#include <hip/hip_runtime.h>
#include <hip/hip_bf16.h>

typedef __attribute__((ext_vector_type(8))) short short8;
typedef __attribute__((ext_vector_type(4))) short bfx4;
typedef __attribute__((ext_vector_type(4))) float floatx4;

#define SEQ     2048
#define DMODEL  768
#define DINNER  1536
#define DSTATE  128
#define NH      24
#define CONVDIM 1792
#define NPROJ   3352   // 2*DINNER + 2*DSTATE + NH
#define QCH     64     // SSD chunk length
#define NCH     (SEQ / QCH)   // 32 chunks

__device__ inline float bf2f(short s) {
    return __uint_as_float(((unsigned)(unsigned short)s) << 16);
}
__device__ inline short f2bf(float f) {
    __hip_bfloat16 h = __float2bfloat16(f);
    return *reinterpret_cast<short*>(&h);
}
__device__ inline void gl_lds16(const void* g, void* l) {
    __builtin_amdgcn_global_load_lds((const __attribute__((address_space(1))) unsigned int*)g,
                                     (__attribute__((address_space(3))) unsigned int*)l, 16, 0, 0);
}

// ---------------------------------------------------------------- converts (float4)
__global__ __launch_bounds__(256) void cvt_kernel(const float* __restrict__ src,
                                                  __hip_bfloat16* __restrict__ dst, int n4) {
    int i = blockIdx.x * 256 + threadIdx.x;
    if (i >= n4) return;
    float4 v = *(const float4*)(src + (size_t)i * 4);
    bfx4 o = { f2bf(v.x), f2bf(v.y), f2bf(v.z), f2bf(v.w) };
    *(bfx4*)((short*)dst + (size_t)i * 4) = o;
}

// Build A1[dir][b*SEQ+t][k] = bf16(x[b][dir? SEQ-1-t : t][k]); 4 elems/thread
__global__ __launch_bounds__(256) void prep_x_kernel(const float* __restrict__ x,
                                                     __hip_bfloat16* __restrict__ A1) {
    size_t i4 = (size_t)blockIdx.x * 256 + threadIdx.x;
    const size_t total4 = (size_t)2 * 2 * SEQ * DMODEL / 4;
    if (i4 >= total4) return;
    size_t idx = i4 * 4;
    int k = (int)(idx % DMODEL);
    size_t m = idx / DMODEL;
    int dir = (int)(m >> 12);
    int mm  = (int)(m & 4095);
    int b = mm >> 11, t = mm & 2047;
    int ts = dir ? (SEQ - 1 - t) : t;
    float4 v = *(const float4*)(x + ((size_t)(b * SEQ + ts)) * DMODEL + k);
    bfx4 o = { f2bf(v.x), f2bf(v.y), f2bf(v.z), f2bf(v.w) };
    *(bfx4*)((short*)A1 + idx) = o;
}

// ---------------------------------------------------------------- GEMM 128x128: C = A[M,K] @ Bw[N,K]^T
// global_load_lds width-16 staging, 4 waves (2x2), 4x4 16x16 accs per wave.
// mode 0: fp32 store. mode 1: C[flip(row)] += v. mode 2: in_proj routing.
__global__ __launch_bounds__(256) void gemm_bt(const __hip_bfloat16* __restrict__ A,
                                               const __hip_bfloat16* __restrict__ Bw,
                                               float* __restrict__ C,
                                               __hip_bfloat16* __restrict__ Zb,
                                               __hip_bfloat16* __restrict__ Xb,
                                               float* __restrict__ DT,
                                               float* __restrict__ LA,
                                               const float* __restrict__ dtbias,
                                               const float* __restrict__ Alog,
                                               int M, int N, int K, int mode) {
    __shared__ __hip_bfloat16 As[128 * 32];   // no padding (global_load_lds layout)
    __shared__ __hip_bfloat16 Bs[128 * 32];
    int tid = threadIdx.x;
    int w = tid >> 6, lane = tid & 63;
    int q = lane >> 4, mm = lane & 15;
    int wm = w >> 1, wn = w & 1;
    int m0 = blockIdx.y * 128, n0 = blockIdx.x * 128;

    int lrow = lane >> 2;          // 0..15
    int lcol = (lane & 3) * 8;     // 0/8/16/24

    floatx4 acc[16];
#pragma unroll
    for (int i = 0; i < 16; i++) acc[i] = (floatx4){0.f, 0.f, 0.f, 0.f};

    for (int k0 = 0; k0 < K; k0 += 32) {
#pragma unroll
        for (int j = 0; j < 2; j++) {
            int lidx = w * 2 + j;                    // 0..7, wave-uniform
            int arow = m0 + lidx * 16 + lrow;        // M multiple of 128 -> in bounds
            gl_lds16(A + (size_t)arow * K + k0 + lcol, (char*)&As[0] + lidx * 1024);
            int brow = n0 + lidx * 16 + lrow; if (brow > N - 1) brow = N - 1;
            gl_lds16(Bw + (size_t)brow * K + k0 + lcol, (char*)&Bs[0] + lidx * 1024);
        }
        __syncthreads();
        short8 af[4], bf[4];
#pragma unroll
        for (int mb = 0; mb < 4; mb++)
            af[mb] = *(const short8*)&As[(wm * 64 + mb * 16 + mm) * 32 + q * 8];
#pragma unroll
        for (int nb = 0; nb < 4; nb++)
            bf[nb] = *(const short8*)&Bs[(wn * 64 + nb * 16 + mm) * 32 + q * 8];
#pragma unroll
        for (int mb = 0; mb < 4; mb++)
#pragma unroll
            for (int nb = 0; nb < 4; nb++)
                acc[mb * 4 + nb] = __builtin_amdgcn_mfma_f32_16x16x32_bf16(af[mb], bf[nb], acc[mb * 4 + nb], 0, 0, 0);
        __syncthreads();
    }

#pragma unroll
    for (int mb = 0; mb < 4; mb++) {
#pragma unroll
        for (int nb = 0; nb < 4; nb++) {
            int col = n0 + wn * 64 + nb * 16 + mm;
            if (col >= N) continue;
#pragma unroll
            for (int r = 0; r < 4; r++) {
                int rr = m0 + wm * 64 + mb * 16 + q * 4 + r;
                float v = acc[mb * 4 + nb][r];
                if (mode == 0) {
                    C[(size_t)rr * N + col] = v;
                } else if (mode == 1) {
                    int b = rr >> 11, t = rr & 2047;
                    int orow = (b << 11) + (2047 - t);
                    C[(size_t)orow * N + col] += v;
                } else {
                    if (col < DINNER) {
                        Zb[(size_t)rr * DINNER + col] = __float2bfloat16(v);
                    } else if (col < DINNER + CONVDIM) {
                        Xb[(size_t)rr * CONVDIM + (col - DINNER)] = __float2bfloat16(v);
                    } else {
                        int hh = col - (DINNER + CONVDIM);
                        float raw = v + dtbias[hh];
                        float dtv = (raw > 20.f) ? raw : log1pf(__expf(raw));
                        float Av  = -__expf(Alog[hh]);
                        DT[(size_t)rr * NH + hh] = dtv;
                        LA[(size_t)rr * NH + hh] = dtv * Av;
                    }
                }
            }
        }
    }
}

// ---------------------------------------------------------------- conv (depthwise K=4) + silu
// thread owns 8 channels; sliding 4-row register window; 16 t per block.
__global__ __launch_bounds__(256) void conv_kernel(const __hip_bfloat16* __restrict__ Xb,
                                                   const float* __restrict__ conv_w,
                                                   const float* __restrict__ conv_b,
                                                   __hip_bfloat16* __restrict__ xh,
                                                   __hip_bfloat16* __restrict__ Bm,
                                                   __hip_bfloat16* __restrict__ Cm) {
    int db  = blockIdx.x >> 7;            // 4 db x 128 tgroups
    int dir = db >> 1;
    int t0  = (blockIdx.x & 127) * 16;
    int c8  = threadIdx.x * 8;
    if (c8 >= CONVDIM) return;

    float wk[4][8], bs[8];
#pragma unroll
    for (int j = 0; j < 8; j++) {
        bs[j] = conv_b[dir * CONVDIM + c8 + j];
#pragma unroll
        for (int k = 0; k < 4; k++) wk[k][j] = conv_w[((size_t)dir * CONVDIM + c8 + j) * 4 + k];
    }

    const short* xrow = (const short*)Xb + (size_t)db * SEQ * CONVDIM + c8;
    short8 win[4];
    const short8 zer = {0, 0, 0, 0, 0, 0, 0, 0};
#pragma unroll
    for (int k = 0; k < 3; k++) {
        int ts = t0 - 3 + k;
        win[k] = (ts >= 0) ? *(const short8*)(xrow + (size_t)ts * CONVDIM) : zer;
    }

    for (int tt = 0; tt < 16; tt++) {
        int t = t0 + tt;
        win[3] = *(const short8*)(xrow + (size_t)t * CONVDIM);
        short8 outv;
#pragma unroll
        for (int j = 0; j < 8; j++) {
            float acc = bs[j];
#pragma unroll
            for (int k = 0; k < 4; k++) acc += wk[k][j] * bf2f(win[k][j]);
            float sv = acc / (1.f + __expf(-acc));
            outv[j] = f2bf(sv);
        }
        if (c8 < DINNER)
            *(short8*)((short*)xh + (size_t)(db * SEQ + t) * DINNER + c8) = outv;
        else if (c8 < DINNER + DSTATE)
            *(short8*)((short*)Bm + (size_t)(db * SEQ + t) * DSTATE + (c8 - DINNER)) = outv;
        else
            *(short8*)((short*)Cm + (size_t)(db * SEQ + t) * DSTATE + (c8 - DINNER - DSTATE)) = outv;
        win[0] = win[1]; win[1] = win[2]; win[2] = win[3];
    }
}

// ---------------------------------------------------------------- SSD pass 1
__global__ __launch_bounds__(256) void ssd1_kernel(const __hip_bfloat16* __restrict__ XH,
                                                   const __hip_bfloat16* __restrict__ BMh,
                                                   const float* __restrict__ DT,
                                                   const float* __restrict__ LA,
                                                   short* __restrict__ SS,
                                                   float* __restrict__ CUM) {
    int blk = blockIdx.x;
    int ck = blk & 31;
    int dbh = blk >> 5;
    int hh = dbh % NH, db = dbh / NH;
    int base_row = db * SEQ + ck * QCH;

    __shared__ float cum_s[QCH], dt_s[QCH];
    __shared__ short Xt[64][72];
    __shared__ short Bt[128][72];

    int tid = threadIdx.x;
    int lane = tid & 63, w = tid >> 6;
    int q = lane >> 4, mm = lane & 15;

    if (tid < QCH) {
        float la  = LA[(size_t)(base_row + tid) * NH + hh];
        float dtv = DT[(size_t)(base_row + tid) * NH + hh];
        float cs = la;
#pragma unroll
        for (int d = 1; d < 64; d <<= 1) {
            float u = __shfl_up(cs, d);
            if (tid >= d) cs += u;
        }
        cum_s[tid] = cs;
        dt_s[tid] = dtv;
        CUM[(size_t)dbh * SEQ + ck * QCH + tid] = cs;
    }
    __syncthreads();
    float cumL = cum_s[QCH - 1];

    {
        int s2 = (tid & 31) * 2, pb = tid >> 5;
        float f0 = dt_s[s2]     * __expf(cumL - cum_s[s2]);
        float f1 = dt_s[s2 + 1] * __expf(cumL - cum_s[s2 + 1]);
        const short* r0 = (const short*)XH + (size_t)(base_row + s2) * DINNER + hh * 64 + pb * 8;
        const short* r1 = r0 + DINNER;
        short8 x0 = *(const short8*)r0;
        short8 x1 = *(const short8*)r1;
#pragma unroll
        for (int j = 0; j < 8; j++) {
            unsigned lo = (unsigned short)f2bf(f0 * bf2f(x0[j]));
            unsigned hi = (unsigned short)f2bf(f1 * bf2f(x1[j]));
            *(unsigned*)&Xt[pb * 8 + j][s2] = lo | (hi << 16);
        }
    }
    {
        int s2 = (tid & 31) * 2, nb = tid >> 5;
        const short* r0 = (const short*)BMh + (size_t)(base_row + s2) * DSTATE + nb * 16;
        const short* r1 = r0 + DSTATE;
        short8 b0a = *(const short8*)r0,  b0b = *(const short8*)(r0 + 8);
        short8 b1a = *(const short8*)r1,  b1b = *(const short8*)(r1 + 8);
#pragma unroll
        for (int j = 0; j < 8; j++) {
            *(unsigned*)&Bt[nb * 16 + j][s2] =
                (unsigned)(unsigned short)b0a[j] | ((unsigned)(unsigned short)b1a[j] << 16);
            *(unsigned*)&Bt[nb * 16 + 8 + j][s2] =
                (unsigned)(unsigned short)b0b[j] | ((unsigned)(unsigned short)b1b[j] << 16);
        }
    }
    __syncthreads();

    floatx4 acc[8];
#pragma unroll
    for (int i = 0; i < 8; i++) acc[i] = (floatx4){0.f, 0.f, 0.f, 0.f};
#pragma unroll
    for (int kk = 0; kk < 2; kk++) {
        short8 a = *(const short8*)&Xt[w * 16 + mm][kk * 32 + q * 8];
#pragma unroll
        for (int cb = 0; cb < 8; cb++) {
            short8 b = *(const short8*)&Bt[cb * 16 + mm][kk * 32 + q * 8];
            acc[cb] = __builtin_amdgcn_mfma_f32_16x16x32_bf16(a, b, acc[cb], 0, 0, 0);
        }
    }
    short* Sp = SS + (size_t)blk * 8192;
#pragma unroll
    for (int cb = 0; cb < 8; cb++)
#pragma unroll
        for (int r = 0; r < 4; r++)
            Sp[(w * 16 + q * 4 + r) * DSTATE + cb * 16 + mm] = f2bf(acc[cb][r]);
}

// ---------------------------------------------------------------- SSD pass 2: inter-chunk scan
__global__ __launch_bounds__(256) void ssd2_kernel(const short* __restrict__ SS,
                                                   const float* __restrict__ CUM,
                                                   short* __restrict__ Hprev) {
    int dbh = blockIdx.x;
    int tid = threadIdx.x;
    size_t base = (size_t)dbh * NCH * 8192;
    float h[32];
#pragma unroll
    for (int k = 0; k < 32; k++) h[k] = 0.f;
    for (int c = 0; c < NCH; c++) {
        float W = __expf(CUM[(size_t)dbh * SEQ + c * QCH + QCH - 1]);
        size_t cb = base + (size_t)c * 8192;
#pragma unroll
        for (int k = 0; k < 32; k++) {
            int idx = k * 256 + tid;
            Hprev[cb + idx] = f2bf(h[k]);
            h[k] = h[k] * W + bf2f(SS[cb + idx]);
        }
    }
}

// ---------------------------------------------------------------- SSD pass 3
__global__ __launch_bounds__(256) void ssd3_kernel(const __hip_bfloat16* __restrict__ XH,
                                                   const __hip_bfloat16* __restrict__ BMh,
                                                   const __hip_bfloat16* __restrict__ CMh,
                                                   const float* __restrict__ DT,
                                                   const float* __restrict__ CUM,
                                                   const short* __restrict__ Hprev,
                                                   __hip_bfloat16* __restrict__ Yb) {
    int blk = blockIdx.x;
    int ck = blk & 31;
    int dbh = blk >> 5;
    int hh = dbh % NH, db = dbh / NH;
    int base_row = db * SEQ + ck * QCH;

    __shared__ float cum_s[QCH], dt_s[QCH];
    __shared__ short Ct[64][136];
    __shared__ short G[64][72];
    __shared__ short Xt[64][72];

    int tid = threadIdx.x;
    int lane = tid & 63, w = tid >> 6;
    int q = lane >> 4, mm = lane & 15;

    if (tid < QCH) {
        cum_s[tid] = CUM[(size_t)dbh * SEQ + ck * QCH + tid];
        dt_s[tid]  = DT[(size_t)(base_row + tid) * NH + hh];
    }

    const short* Cg = (const short*)CMh + (size_t)base_row * DSTATE;
    const short* Bg = (const short*)BMh + (size_t)base_row * DSTATE;
    floatx4 P[4];
#pragma unroll
    for (int i = 0; i < 4; i++) P[i] = (floatx4){0.f, 0.f, 0.f, 0.f};
#pragma unroll
    for (int kk = 0; kk < 4; kk++) {
        short8 a = *(const short8*)(Cg + (size_t)(w * 16 + mm) * DSTATE + kk * 32 + q * 8);
#pragma unroll
        for (int cb = 0; cb < 4; cb++) {
            short8 b = *(const short8*)(Bg + (size_t)(cb * 16 + mm) * DSTATE + kk * 32 + q * 8);
            P[cb] = __builtin_amdgcn_mfma_f32_16x16x32_bf16(a, b, P[cb], 0, 0, 0);
        }
    }
    __syncthreads();

    {
        int t = tid & 63, nb4 = tid >> 6;
        float wt = __expf(cum_s[t]);
        const short* src = Cg + (size_t)t * DSTATE + nb4 * 32;
#pragma unroll
        for (int u = 0; u < 2; u++) {
            short8 v = *(const short8*)(src + u * 16);
            short8 v2 = *(const short8*)(src + u * 16 + 8);
#pragma unroll
            for (int j = 0; j < 4; j++) {
                unsigned lo = (unsigned short)f2bf(wt * bf2f(v[2 * j]));
                unsigned hi = (unsigned short)f2bf(wt * bf2f(v[2 * j + 1]));
                *(unsigned*)&Ct[t][nb4 * 32 + u * 16 + 2 * j] = lo | (hi << 16);
                lo = (unsigned short)f2bf(wt * bf2f(v2[2 * j]));
                hi = (unsigned short)f2bf(wt * bf2f(v2[2 * j + 1]));
                *(unsigned*)&Ct[t][nb4 * 32 + u * 16 + 8 + 2 * j] = lo | (hi << 16);
            }
        }
    }
    {
        int s2 = (tid & 31) * 2, pb = tid >> 5;
        const short* r0 = (const short*)XH + (size_t)(base_row + s2) * DINNER + hh * 64 + pb * 8;
        const short* r1 = r0 + DINNER;
        short8 x0 = *(const short8*)r0;
        short8 x1 = *(const short8*)r1;
#pragma unroll
        for (int j = 0; j < 8; j++) {
            *(unsigned*)&Xt[pb * 8 + j][s2] =
                (unsigned)(unsigned short)x0[j] | ((unsigned)(unsigned short)x1[j] << 16);
        }
    }
#pragma unroll
    for (int cb = 0; cb < 4; cb++) {
#pragma unroll
        for (int r = 0; r < 4; r++) {
            int t = w * 16 + q * 4 + r;
            int s = cb * 16 + mm;
            float g = (s <= t) ? P[cb][r] * __expf(cum_s[t] - cum_s[s]) * dt_s[s] : 0.f;
            G[t][s] = f2bf(g);
        }
    }
    __syncthreads();

    floatx4 Y[4];
#pragma unroll
    for (int i = 0; i < 4; i++) Y[i] = (floatx4){0.f, 0.f, 0.f, 0.f};
#pragma unroll
    for (int kk = 0; kk < 2; kk++) {
        short8 a = *(const short8*)&G[w * 16 + mm][kk * 32 + q * 8];
#pragma unroll
        for (int cb = 0; cb < 4; cb++) {
            short8 b = *(const short8*)&Xt[cb * 16 + mm][kk * 32 + q * 8];
            Y[cb] = __builtin_amdgcn_mfma_f32_16x16x32_bf16(a, b, Y[cb], 0, 0, 0);
        }
    }
    const short* Hc = Hprev + (size_t)blk * 8192;
#pragma unroll
    for (int kk = 0; kk < 4; kk++) {
        short8 a = *(const short8*)&Ct[w * 16 + mm][kk * 32 + q * 8];
#pragma unroll
        for (int cb = 0; cb < 4; cb++) {
            short8 b = *(const short8*)(Hc + (size_t)(cb * 16 + mm) * DSTATE + kk * 32 + q * 8);
            Y[cb] = __builtin_amdgcn_mfma_f32_16x16x32_bf16(a, b, Y[cb], 0, 0, 0);
        }
    }
#pragma unroll
    for (int cb = 0; cb < 4; cb++)
#pragma unroll
        for (int r = 0; r < 4; r++)
            Yb[(size_t)(base_row + w * 16 + q * 4 + r) * DINNER + hh * 64 + cb * 16 + mm] =
                __float2bfloat16(Y[cb][r]);
}

// ---------------------------------------------------------------- gating + RMSNorm (192 thr x 8 ch, vectorized)
__global__ __launch_bounds__(192) void gate_kernel(const __hip_bfloat16* __restrict__ Yb,
                                                   const __hip_bfloat16* __restrict__ xh,
                                                   const __hip_bfloat16* __restrict__ Zb,
                                                   const float* __restrict__ Dp,
                                                   const float* __restrict__ norm_w,
                                                   __hip_bfloat16* __restrict__ A2) {
    int row = blockIdx.x;
    int dir = row >> 12;
    int c8 = threadIdx.x * 8;
    int hd = c8 >> 6;
    const short* yr = (const short*)Yb + (size_t)row * DINNER + c8;
    const short* xr = (const short*)xh + (size_t)row * DINNER + c8;
    const short* zr = (const short*)Zb + (size_t)row * DINNER + c8;

    short8 y8 = *(const short8*)yr;
    short8 x8 = *(const short8*)xr;
    short8 z8 = *(const short8*)zr;
    float Dv = Dp[dir * NH + hd];

    float vals[8];
    float ss = 0.f;
#pragma unroll
    for (int j = 0; j < 8; j++) {
        float v = bf2f(y8[j]) + Dv * bf2f(x8[j]);
        float z = bf2f(z8[j]);
        v *= z / (1.f + __expf(-z));
        vals[j] = v;
        ss += v * v;
    }
#pragma unroll
    for (int off = 32; off; off >>= 1) ss += __shfl_down(ss, off);
    __shared__ float ls[3];
    if ((threadIdx.x & 63) == 0) ls[threadIdx.x >> 6] = ss;
    __syncthreads();
    float tot = ls[0] + ls[1] + ls[2];
    float scale = rsqrtf(tot / (float)DINNER + 1e-5f);

    const float* nw = norm_w + dir * DINNER + c8;
    short8 o;
#pragma unroll
    for (int j = 0; j < 8; j++) o[j] = f2bf(vals[j] * scale * nw[j]);
    *(short8*)((short*)A2 + (size_t)row * DINNER + c8) = o;
}

// ---------------------------------------------------------------- launch
extern "C" void kernel_launch(void* const* d_in, const int* in_sizes, int n_in,
                              void* d_out, int out_size, void* d_ws, size_t ws_size,
                              hipStream_t stream) {
    const float* x        = (const float*)d_in[0];
    const float* in_w     = (const float*)d_in[1];
    const float* conv_w   = (const float*)d_in[2];
    const float* conv_b   = (const float*)d_in[3];
    const float* dt_bias  = (const float*)d_in[4];
    const float* A_log    = (const float*)d_in[5];
    const float* Dp       = (const float*)d_in[6];
    const float* norm_w   = (const float*)d_in[7];
    const float* out_w    = (const float*)d_in[8];
    float* out = (float*)d_out;

    const size_t szW2 = (size_t)2 * DMODEL * DINNER * 2;
    const size_t szZ  = (size_t)8192 * DINNER * 2;
    const size_t szXH = (size_t)8192 * DINNER * 2;
    const size_t szBM = (size_t)8192 * DSTATE * 2;
    const size_t szCM = szBM;
    const size_t szDT = (size_t)8192 * NH * 4;
    const size_t szLA = szDT;
    const size_t szA1 = (size_t)8192 * DMODEL * 2;
    const size_t szW1 = (size_t)2 * NPROJ * DMODEL * 2;
    const size_t szXB = (size_t)8192 * CONVDIM * 2;
    const size_t szYb = (size_t)8192 * DINNER * 2;
    const size_t szSS = (size_t)96 * NCH * 8192 * 2;
    const size_t szRa = szA1 + szW1 + szXB;
    size_t szR = szRa;
    if (szR < szYb) szR = szYb;
    if (szR < szSS) szR = szSS;
    const size_t szHp = szSS;
    const size_t szCU = (size_t)96 * SEQ * 4;

    char* ws = (char*)d_ws;
    size_t off = 0;
    auto alloc = [&](size_t bytes) { char* p = ws + off; off += (bytes + 255) & ~(size_t)255; return p; };

    __hip_bfloat16* W2 = (__hip_bfloat16*)alloc(szW2);
    __hip_bfloat16* Z  = (__hip_bfloat16*)alloc(szZ);
    __hip_bfloat16* XH = (__hip_bfloat16*)alloc(szXH);
    __hip_bfloat16* BM = (__hip_bfloat16*)alloc(szBM);
    __hip_bfloat16* CM = (__hip_bfloat16*)alloc(szCM);
    float* DT = (float*)alloc(szDT);
    float* LA = (float*)alloc(szLA);
    char*  R  = (char*)alloc(szR);
    __hip_bfloat16* A1  = (__hip_bfloat16*)R;
    __hip_bfloat16* W1  = (__hip_bfloat16*)(R + szA1);
    __hip_bfloat16* XBC = (__hip_bfloat16*)(R + szA1 + szW1);
    short* SS = (short*)R;
    __hip_bfloat16* Yb = (__hip_bfloat16*)R;

    short* Hp = (short*)alloc(szHp);
    float* CU = (float*)alloc(szCU);
    if (off > ws_size) return;   // clean fail instead of OOB crash

    // 1. weight converts (float4)
    int n1 = 2 * NPROJ * DMODEL / 4;
    cvt_kernel<<<(n1 + 255) / 256, 256, 0, stream>>>(in_w, W1, n1);
    int n2 = 2 * DMODEL * DINNER / 4;
    cvt_kernel<<<(n2 + 255) / 256, 256, 0, stream>>>(out_w, W2, n2);
    // 2. x -> bf16 (flipped copy for dir 1)
    int n3 = 2 * 4096 * DMODEL / 4;
    prep_x_kernel<<<(n3 + 255) / 256, 256, 0, stream>>>(x, A1);

    // 3. in_proj GEMMs (128-tile) with routing epilogue
    {
        dim3 grid((NPROJ + 127) / 128, 4096 / 128);
        for (int dir = 0; dir < 2; dir++) {
            gemm_bt<<<grid, 256, 0, stream>>>(A1 + (size_t)dir * 4096 * DMODEL,
                                              W1 + (size_t)dir * NPROJ * DMODEL,
                                              nullptr,
                                              Z   + (size_t)dir * 4096 * DINNER,
                                              XBC + (size_t)dir * 4096 * CONVDIM,
                                              DT  + (size_t)dir * 4096 * NH,
                                              LA  + (size_t)dir * 4096 * NH,
                                              dt_bias + dir * NH,
                                              A_log   + dir * NH,
                                              4096, NPROJ, DMODEL, 2);
        }
    }

    // 4. conv + silu (vectorized sliding window)
    conv_kernel<<<4 * 128, 256, 0, stream>>>(XBC, conv_w, conv_b, XH, BM, CM);

    // 5. SSD chunked scan
    ssd1_kernel<<<4 * NH * NCH, 256, 0, stream>>>(XH, BM, DT, LA, SS, CU);
    ssd2_kernel<<<4 * NH, 256, 0, stream>>>(SS, CU, Hp);
    ssd3_kernel<<<4 * NH * NCH, 256, 0, stream>>>(XH, BM, CM, DT, CU, Hp, Yb);

    // 6. gating + RMSNorm (A2 == Z, in-place)
    gate_kernel<<<2 * 4096, 192, 0, stream>>>(Yb, XH, Z, Dp, norm_w, Z);

    // 7. out_proj GEMMs (128-tile); dir0 overwrites, dir1 flip-adds
    {
        dim3 grid(DMODEL / 128, 4096 / 128);
        gemm_bt<<<grid, 256, 0, stream>>>(Z, W2, out,
                                          nullptr, nullptr, nullptr, nullptr, nullptr, nullptr,
                                          4096, DMODEL, DINNER, 0);
        gemm_bt<<<grid, 256, 0, stream>>>(Z + (size_t)4096 * DINNER,
                                          W2 + (size_t)DMODEL * DINNER,
                                          out,
                                          nullptr, nullptr, nullptr, nullptr, nullptr, nullptr,
                                          4096, DMODEL, DINNER, 1);
    }
}

// Round 8
// 452.568 us; speedup vs baseline: 3.8259x; 1.1125x over previous
//
#include <hip/hip_runtime.h>
#include <hip/hip_bf16.h>

typedef __attribute__((ext_vector_type(8))) short short8;
typedef __attribute__((ext_vector_type(4))) short bfx4;
typedef __attribute__((ext_vector_type(4))) float floatx4;

#define SEQ     2048
#define DMODEL  768
#define DINNER  1536
#define DSTATE  128
#define NH      24
#define CONVDIM 1792
#define NPROJ   3352   // 2*DINNER + 2*DSTATE + NH
#define QCH     64     // SSD chunk length
#define NCH     (SEQ / QCH)   // 32 chunks

__device__ inline float bf2f(short s) {
    return __uint_as_float(((unsigned)(unsigned short)s) << 16);
}
__device__ inline short f2bf(float f) {
    __hip_bfloat16 h = __float2bfloat16(f);
    return *reinterpret_cast<short*>(&h);
}
__device__ inline void gl_lds16(const void* g, void* l) {
    __builtin_amdgcn_global_load_lds((const __attribute__((address_space(1))) unsigned int*)g,
                                     (__attribute__((address_space(3))) unsigned int*)l, 16, 0, 0);
}

// ---------------------------------------------------------------- converts (float4)
__global__ __launch_bounds__(256) void cvt_kernel(const float* __restrict__ src,
                                                  __hip_bfloat16* __restrict__ dst, int n4) {
    int i = blockIdx.x * 256 + threadIdx.x;
    if (i >= n4) return;
    float4 v = *(const float4*)(src + (size_t)i * 4);
    bfx4 o = { f2bf(v.x), f2bf(v.y), f2bf(v.z), f2bf(v.w) };
    *(bfx4*)((short*)dst + (size_t)i * 4) = o;
}

// Build A1[dir][b*SEQ+t][k] = bf16(x[b][dir? SEQ-1-t : t][k]); 4 elems/thread
__global__ __launch_bounds__(256) void prep_x_kernel(const float* __restrict__ x,
                                                     __hip_bfloat16* __restrict__ A1) {
    size_t i4 = (size_t)blockIdx.x * 256 + threadIdx.x;
    const size_t total4 = (size_t)2 * 2 * SEQ * DMODEL / 4;
    if (i4 >= total4) return;
    size_t idx = i4 * 4;
    int k = (int)(idx % DMODEL);
    size_t m = idx / DMODEL;
    int dir = (int)(m >> 12);
    int mm  = (int)(m & 4095);
    int b = mm >> 11, t = mm & 2047;
    int ts = dir ? (SEQ - 1 - t) : t;
    float4 v = *(const float4*)(x + ((size_t)(b * SEQ + ts)) * DMODEL + k);
    bfx4 o = { f2bf(v.x), f2bf(v.y), f2bf(v.z), f2bf(v.w) };
    *(bfx4*)((short*)A1 + idx) = o;
}

// ---------------------------------------------------------------- GEMM 128x128, BK=64
// global_load_lds width-16 staging with XOR swizzle; 4 waves (2x2), 4x4 accs.
// LDS row r stores global 16B-chunk g at position g^(r&7) (swizzle kills bank conflicts).
// mode 0: fp32 store. mode 1: C[flip(row)] += v. mode 2: in_proj routing.
__global__ __launch_bounds__(256) void gemm_bt(const __hip_bfloat16* __restrict__ A,
                                               const __hip_bfloat16* __restrict__ Bw,
                                               float* __restrict__ C,
                                               __hip_bfloat16* __restrict__ Zb,
                                               __hip_bfloat16* __restrict__ Xb,
                                               float* __restrict__ DT,
                                               float* __restrict__ LA,
                                               const float* __restrict__ dtbias,
                                               const float* __restrict__ Alog,
                                               int M, int N, int K, int mode) {
    __shared__ __hip_bfloat16 As[128 * 64];   // 16 KB
    __shared__ __hip_bfloat16 Bs[128 * 64];   // 16 KB
    int tid = threadIdx.x;
    int w = tid >> 6, lane = tid & 63;
    int q = lane >> 4, mm = lane & 15;
    int wm = w >> 1, wn = w & 1;
    int m0 = blockIdx.x * 128, n0 = blockIdx.y * 128;

    int lr = lane >> 3;                    // 0..7 (row within 8-row group)
    int lc = ((lane & 7) ^ lr) * 8;        // swizzled source chunk (elements)

    floatx4 acc[16];
#pragma unroll
    for (int i = 0; i < 16; i++) acc[i] = (floatx4){0.f, 0.f, 0.f, 0.f};

    for (int k0 = 0; k0 < K; k0 += 64) {
#pragma unroll
        for (int j = 0; j < 4; j++) {
            int lidx = w * 4 + j;                    // 0..15, wave-uniform
            int arow = m0 + lidx * 8 + lr;           // M multiple of 128 -> in bounds
            gl_lds16(A + (size_t)arow * K + k0 + lc, (char*)&As[0] + lidx * 1024);
            int brow = n0 + lidx * 8 + lr; if (brow > N - 1) brow = N - 1;
            gl_lds16(Bw + (size_t)brow * K + k0 + lc, (char*)&Bs[0] + lidx * 1024);
        }
        __syncthreads();
#pragma unroll
        for (int kk = 0; kk < 2; kk++) {
            short8 af[4], bf[4];
#pragma unroll
            for (int mb = 0; mb < 4; mb++) {
                int R = wm * 64 + mb * 16 + mm;
                af[mb] = *(const short8*)&As[R * 64 + (((kk * 4 + q) ^ (mm & 7)) * 8)];
            }
#pragma unroll
            for (int nb = 0; nb < 4; nb++) {
                int R = wn * 64 + nb * 16 + mm;
                bf[nb] = *(const short8*)&Bs[R * 64 + (((kk * 4 + q) ^ (mm & 7)) * 8)];
            }
#pragma unroll
            for (int mb = 0; mb < 4; mb++)
#pragma unroll
                for (int nb = 0; nb < 4; nb++)
                    acc[mb * 4 + nb] = __builtin_amdgcn_mfma_f32_16x16x32_bf16(af[mb], bf[nb], acc[mb * 4 + nb], 0, 0, 0);
        }
        __syncthreads();
    }

#pragma unroll
    for (int mb = 0; mb < 4; mb++) {
#pragma unroll
        for (int nb = 0; nb < 4; nb++) {
            int col = n0 + wn * 64 + nb * 16 + mm;
            if (col >= N) continue;
#pragma unroll
            for (int r = 0; r < 4; r++) {
                int rr = m0 + wm * 64 + mb * 16 + q * 4 + r;
                float v = acc[mb * 4 + nb][r];
                if (mode == 0) {
                    C[(size_t)rr * N + col] = v;
                } else if (mode == 1) {
                    int b = rr >> 11, t = rr & 2047;
                    int orow = (b << 11) + (2047 - t);
                    C[(size_t)orow * N + col] += v;
                } else {
                    if (col < DINNER) {
                        Zb[(size_t)rr * DINNER + col] = __float2bfloat16(v);
                    } else if (col < DINNER + CONVDIM) {
                        Xb[(size_t)rr * CONVDIM + (col - DINNER)] = __float2bfloat16(v);
                    } else {
                        int hh = col - (DINNER + CONVDIM);
                        float raw = v + dtbias[hh];
                        float dtv = (raw > 20.f) ? raw : log1pf(__expf(raw));
                        float Av  = -__expf(Alog[hh]);
                        DT[(size_t)rr * NH + hh] = dtv;
                        LA[(size_t)rr * NH + hh] = dtv * Av;
                    }
                }
            }
        }
    }
}

// ---------------------------------------------------------------- conv (depthwise K=4) + silu
__global__ __launch_bounds__(256) void conv_kernel(const __hip_bfloat16* __restrict__ Xb,
                                                   const float* __restrict__ conv_w,
                                                   const float* __restrict__ conv_b,
                                                   __hip_bfloat16* __restrict__ xh,
                                                   __hip_bfloat16* __restrict__ Bm,
                                                   __hip_bfloat16* __restrict__ Cm) {
    int db  = blockIdx.x >> 7;
    int dir = db >> 1;
    int t0  = (blockIdx.x & 127) * 16;
    int c8  = threadIdx.x * 8;
    if (c8 >= CONVDIM) return;

    float wk[4][8], bs[8];
#pragma unroll
    for (int j = 0; j < 8; j++) {
        bs[j] = conv_b[dir * CONVDIM + c8 + j];
#pragma unroll
        for (int k = 0; k < 4; k++) wk[k][j] = conv_w[((size_t)dir * CONVDIM + c8 + j) * 4 + k];
    }

    const short* xrow = (const short*)Xb + (size_t)db * SEQ * CONVDIM + c8;
    short8 win[4];
    const short8 zer = {0, 0, 0, 0, 0, 0, 0, 0};
#pragma unroll
    for (int k = 0; k < 3; k++) {
        int ts = t0 - 3 + k;
        win[k] = (ts >= 0) ? *(const short8*)(xrow + (size_t)ts * CONVDIM) : zer;
    }

    for (int tt = 0; tt < 16; tt++) {
        int t = t0 + tt;
        win[3] = *(const short8*)(xrow + (size_t)t * CONVDIM);
        short8 outv;
#pragma unroll
        for (int j = 0; j < 8; j++) {
            float acc = bs[j];
#pragma unroll
            for (int k = 0; k < 4; k++) acc += wk[k][j] * bf2f(win[k][j]);
            float sv = acc / (1.f + __expf(-acc));
            outv[j] = f2bf(sv);
        }
        if (c8 < DINNER)
            *(short8*)((short*)xh + (size_t)(db * SEQ + t) * DINNER + c8) = outv;
        else if (c8 < DINNER + DSTATE)
            *(short8*)((short*)Bm + (size_t)(db * SEQ + t) * DSTATE + (c8 - DINNER)) = outv;
        else
            *(short8*)((short*)Cm + (size_t)(db * SEQ + t) * DSTATE + (c8 - DINNER - DSTATE)) = outv;
        win[0] = win[1]; win[1] = win[2]; win[2] = win[3];
    }
}

// ---------------------------------------------------------------- SSD pass 1
__global__ __launch_bounds__(256) void ssd1_kernel(const __hip_bfloat16* __restrict__ XH,
                                                   const __hip_bfloat16* __restrict__ BMh,
                                                   const float* __restrict__ DT,
                                                   const float* __restrict__ LA,
                                                   short* __restrict__ SS,
                                                   float* __restrict__ CUM) {
    int blk = blockIdx.x;
    int ck = blk & 31;
    int dbh = blk >> 5;
    int hh = dbh % NH, db = dbh / NH;
    int base_row = db * SEQ + ck * QCH;

    __shared__ float cum_s[QCH], dt_s[QCH];
    __shared__ short Xt[64][72];
    __shared__ short Bt[128][72];

    int tid = threadIdx.x;
    int lane = tid & 63, w = tid >> 6;
    int q = lane >> 4, mm = lane & 15;

    if (tid < QCH) {
        float la  = LA[(size_t)(base_row + tid) * NH + hh];
        float dtv = DT[(size_t)(base_row + tid) * NH + hh];
        float cs = la;
#pragma unroll
        for (int d = 1; d < 64; d <<= 1) {
            float u = __shfl_up(cs, d);
            if (tid >= d) cs += u;
        }
        cum_s[tid] = cs;
        dt_s[tid] = dtv;
        CUM[(size_t)dbh * SEQ + ck * QCH + tid] = cs;
    }
    __syncthreads();
    float cumL = cum_s[QCH - 1];

    {
        int s2 = (tid & 31) * 2, pb = tid >> 5;
        float f0 = dt_s[s2]     * __expf(cumL - cum_s[s2]);
        float f1 = dt_s[s2 + 1] * __expf(cumL - cum_s[s2 + 1]);
        const short* r0 = (const short*)XH + (size_t)(base_row + s2) * DINNER + hh * 64 + pb * 8;
        const short* r1 = r0 + DINNER;
        short8 x0 = *(const short8*)r0;
        short8 x1 = *(const short8*)r1;
#pragma unroll
        for (int j = 0; j < 8; j++) {
            unsigned lo = (unsigned short)f2bf(f0 * bf2f(x0[j]));
            unsigned hi = (unsigned short)f2bf(f1 * bf2f(x1[j]));
            *(unsigned*)&Xt[pb * 8 + j][s2] = lo | (hi << 16);
        }
    }
    {
        int s2 = (tid & 31) * 2, nb = tid >> 5;
        const short* r0 = (const short*)BMh + (size_t)(base_row + s2) * DSTATE + nb * 16;
        const short* r1 = r0 + DSTATE;
        short8 b0a = *(const short8*)r0,  b0b = *(const short8*)(r0 + 8);
        short8 b1a = *(const short8*)r1,  b1b = *(const short8*)(r1 + 8);
#pragma unroll
        for (int j = 0; j < 8; j++) {
            *(unsigned*)&Bt[nb * 16 + j][s2] =
                (unsigned)(unsigned short)b0a[j] | ((unsigned)(unsigned short)b1a[j] << 16);
            *(unsigned*)&Bt[nb * 16 + 8 + j][s2] =
                (unsigned)(unsigned short)b0b[j] | ((unsigned)(unsigned short)b1b[j] << 16);
        }
    }
    __syncthreads();

    floatx4 acc[8];
#pragma unroll
    for (int i = 0; i < 8; i++) acc[i] = (floatx4){0.f, 0.f, 0.f, 0.f};
#pragma unroll
    for (int kk = 0; kk < 2; kk++) {
        short8 a = *(const short8*)&Xt[w * 16 + mm][kk * 32 + q * 8];
#pragma unroll
        for (int cb = 0; cb < 8; cb++) {
            short8 b = *(const short8*)&Bt[cb * 16 + mm][kk * 32 + q * 8];
            acc[cb] = __builtin_amdgcn_mfma_f32_16x16x32_bf16(a, b, acc[cb], 0, 0, 0);
        }
    }
    short* Sp = SS + (size_t)blk * 8192;
#pragma unroll
    for (int cb = 0; cb < 8; cb++)
#pragma unroll
        for (int r = 0; r < 4; r++)
            Sp[(w * 16 + q * 4 + r) * DSTATE + cb * 16 + mm] = f2bf(acc[cb][r]);
}

// ---------------------------------------------------------------- SSD pass 2: inter-chunk scan
// 384 blocks: (dbh, quarter of the 8192 h-elements); short8 vectorized.
__global__ __launch_bounds__(256) void ssd2_kernel(const short* __restrict__ SS,
                                                   const float* __restrict__ CUM,
                                                   short* __restrict__ Hprev) {
    int blk = blockIdx.x;
    int dbh = blk >> 2, part = blk & 3;
    int off = part * 2048 + threadIdx.x * 8;
    size_t base = (size_t)dbh * NCH * 8192 + off;
    float h[8];
#pragma unroll
    for (int j = 0; j < 8; j++) h[j] = 0.f;
    for (int c = 0; c < NCH; c++) {
        float W = __expf(CUM[(size_t)dbh * SEQ + c * QCH + QCH - 1]);
        size_t p = base + (size_t)c * 8192;
        short8 s = *(const short8*)(SS + p);
        short8 o;
#pragma unroll
        for (int j = 0; j < 8; j++) o[j] = f2bf(h[j]);
        *(short8*)(Hprev + p) = o;
#pragma unroll
        for (int j = 0; j < 8; j++) h[j] = fmaf(h[j], W, bf2f(s[j]));
    }
}

// ---------------------------------------------------------------- SSD pass 3
__global__ __launch_bounds__(256) void ssd3_kernel(const __hip_bfloat16* __restrict__ XH,
                                                   const __hip_bfloat16* __restrict__ BMh,
                                                   const __hip_bfloat16* __restrict__ CMh,
                                                   const float* __restrict__ DT,
                                                   const float* __restrict__ CUM,
                                                   const short* __restrict__ Hprev,
                                                   __hip_bfloat16* __restrict__ Yb) {
    int blk = blockIdx.x;
    int ck = blk & 31;
    int dbh = blk >> 5;
    int hh = dbh % NH, db = dbh / NH;
    int base_row = db * SEQ + ck * QCH;

    __shared__ float cum_s[QCH], dt_s[QCH];
    __shared__ short Ct[64][136];
    __shared__ short G[64][72];
    __shared__ short Xt[64][72];

    int tid = threadIdx.x;
    int lane = tid & 63, w = tid >> 6;
    int q = lane >> 4, mm = lane & 15;

    if (tid < QCH) {
        cum_s[tid] = CUM[(size_t)dbh * SEQ + ck * QCH + tid];
        dt_s[tid]  = DT[(size_t)(base_row + tid) * NH + hh];
    }

    const short* Cg = (const short*)CMh + (size_t)base_row * DSTATE;
    const short* Bg = (const short*)BMh + (size_t)base_row * DSTATE;
    floatx4 P[4];
#pragma unroll
    for (int i = 0; i < 4; i++) P[i] = (floatx4){0.f, 0.f, 0.f, 0.f};
#pragma unroll
    for (int kk = 0; kk < 4; kk++) {
        short8 a = *(const short8*)(Cg + (size_t)(w * 16 + mm) * DSTATE + kk * 32 + q * 8);
#pragma unroll
        for (int cb = 0; cb < 4; cb++) {
            short8 b = *(const short8*)(Bg + (size_t)(cb * 16 + mm) * DSTATE + kk * 32 + q * 8);
            P[cb] = __builtin_amdgcn_mfma_f32_16x16x32_bf16(a, b, P[cb], 0, 0, 0);
        }
    }
    __syncthreads();

    {
        int t = tid & 63, nb4 = tid >> 6;
        float wt = __expf(cum_s[t]);
        const short* src = Cg + (size_t)t * DSTATE + nb4 * 32;
#pragma unroll
        for (int u = 0; u < 2; u++) {
            short8 v = *(const short8*)(src + u * 16);
            short8 v2 = *(const short8*)(src + u * 16 + 8);
#pragma unroll
            for (int j = 0; j < 4; j++) {
                unsigned lo = (unsigned short)f2bf(wt * bf2f(v[2 * j]));
                unsigned hi = (unsigned short)f2bf(wt * bf2f(v[2 * j + 1]));
                *(unsigned*)&Ct[t][nb4 * 32 + u * 16 + 2 * j] = lo | (hi << 16);
                lo = (unsigned short)f2bf(wt * bf2f(v2[2 * j]));
                hi = (unsigned short)f2bf(wt * bf2f(v2[2 * j + 1]));
                *(unsigned*)&Ct[t][nb4 * 32 + u * 16 + 8 + 2 * j] = lo | (hi << 16);
            }
        }
    }
    {
        int s2 = (tid & 31) * 2, pb = tid >> 5;
        const short* r0 = (const short*)XH + (size_t)(base_row + s2) * DINNER + hh * 64 + pb * 8;
        const short* r1 = r0 + DINNER;
        short8 x0 = *(const short8*)r0;
        short8 x1 = *(const short8*)r1;
#pragma unroll
        for (int j = 0; j < 8; j++) {
            *(unsigned*)&Xt[pb * 8 + j][s2] =
                (unsigned)(unsigned short)x0[j] | ((unsigned)(unsigned short)x1[j] << 16);
        }
    }
#pragma unroll
    for (int cb = 0; cb < 4; cb++) {
#pragma unroll
        for (int r = 0; r < 4; r++) {
            int t = w * 16 + q * 4 + r;
            int s = cb * 16 + mm;
            float g = (s <= t) ? P[cb][r] * __expf(cum_s[t] - cum_s[s]) * dt_s[s] : 0.f;
            G[t][s] = f2bf(g);
        }
    }
    __syncthreads();

    floatx4 Y[4];
#pragma unroll
    for (int i = 0; i < 4; i++) Y[i] = (floatx4){0.f, 0.f, 0.f, 0.f};
#pragma unroll
    for (int kk = 0; kk < 2; kk++) {
        short8 a = *(const short8*)&G[w * 16 + mm][kk * 32 + q * 8];
#pragma unroll
        for (int cb = 0; cb < 4; cb++) {
            short8 b = *(const short8*)&Xt[cb * 16 + mm][kk * 32 + q * 8];
            Y[cb] = __builtin_amdgcn_mfma_f32_16x16x32_bf16(a, b, Y[cb], 0, 0, 0);
        }
    }
    const short* Hc = Hprev + (size_t)blk * 8192;
#pragma unroll
    for (int kk = 0; kk < 4; kk++) {
        short8 a = *(const short8*)&Ct[w * 16 + mm][kk * 32 + q * 8];
#pragma unroll
        for (int cb = 0; cb < 4; cb++) {
            short8 b = *(const short8*)(Hc + (size_t)(cb * 16 + mm) * DSTATE + kk * 32 + q * 8);
            Y[cb] = __builtin_amdgcn_mfma_f32_16x16x32_bf16(a, b, Y[cb], 0, 0, 0);
        }
    }
#pragma unroll
    for (int cb = 0; cb < 4; cb++)
#pragma unroll
        for (int r = 0; r < 4; r++)
            Yb[(size_t)(base_row + w * 16 + q * 4 + r) * DINNER + hh * 64 + cb * 16 + mm] =
                __float2bfloat16(Y[cb][r]);
}

// ---------------------------------------------------------------- gating + RMSNorm (192 thr x 8 ch)
__global__ __launch_bounds__(192) void gate_kernel(const __hip_bfloat16* __restrict__ Yb,
                                                   const __hip_bfloat16* __restrict__ xh,
                                                   const __hip_bfloat16* __restrict__ Zb,
                                                   const float* __restrict__ Dp,
                                                   const float* __restrict__ norm_w,
                                                   __hip_bfloat16* __restrict__ A2) {
    int row = blockIdx.x;
    int dir = row >> 12;
    int c8 = threadIdx.x * 8;
    int hd = c8 >> 6;
    const short* yr = (const short*)Yb + (size_t)row * DINNER + c8;
    const short* xr = (const short*)xh + (size_t)row * DINNER + c8;
    const short* zr = (const short*)Zb + (size_t)row * DINNER + c8;

    short8 y8 = *(const short8*)yr;
    short8 x8 = *(const short8*)xr;
    short8 z8 = *(const short8*)zr;
    float Dv = Dp[dir * NH + hd];

    float vals[8];
    float ss = 0.f;
#pragma unroll
    for (int j = 0; j < 8; j++) {
        float v = bf2f(y8[j]) + Dv * bf2f(x8[j]);
        float z = bf2f(z8[j]);
        v *= z / (1.f + __expf(-z));
        vals[j] = v;
        ss += v * v;
    }
#pragma unroll
    for (int off = 32; off; off >>= 1) ss += __shfl_down(ss, off);
    __shared__ float ls[3];
    if ((threadIdx.x & 63) == 0) ls[threadIdx.x >> 6] = ss;
    __syncthreads();
    float tot = ls[0] + ls[1] + ls[2];
    float scale = rsqrtf(tot / (float)DINNER + 1e-5f);

    const float* nw = norm_w + dir * DINNER + c8;
    short8 o;
#pragma unroll
    for (int j = 0; j < 8; j++) o[j] = f2bf(vals[j] * scale * nw[j]);
    *(short8*)((short*)A2 + (size_t)row * DINNER + c8) = o;
}

// ---------------------------------------------------------------- launch
extern "C" void kernel_launch(void* const* d_in, const int* in_sizes, int n_in,
                              void* d_out, int out_size, void* d_ws, size_t ws_size,
                              hipStream_t stream) {
    const float* x        = (const float*)d_in[0];
    const float* in_w     = (const float*)d_in[1];
    const float* conv_w   = (const float*)d_in[2];
    const float* conv_b   = (const float*)d_in[3];
    const float* dt_bias  = (const float*)d_in[4];
    const float* A_log    = (const float*)d_in[5];
    const float* Dp       = (const float*)d_in[6];
    const float* norm_w   = (const float*)d_in[7];
    const float* out_w    = (const float*)d_in[8];
    float* out = (float*)d_out;

    const size_t szW2 = (size_t)2 * DMODEL * DINNER * 2;
    const size_t szZ  = (size_t)8192 * DINNER * 2;
    const size_t szXH = (size_t)8192 * DINNER * 2;
    const size_t szBM = (size_t)8192 * DSTATE * 2;
    const size_t szCM = szBM;
    const size_t szDT = (size_t)8192 * NH * 4;
    const size_t szLA = szDT;
    const size_t szA1 = (size_t)8192 * DMODEL * 2;
    const size_t szW1 = (size_t)2 * NPROJ * DMODEL * 2;
    const size_t szXB = (size_t)8192 * CONVDIM * 2;
    const size_t szYb = (size_t)8192 * DINNER * 2;
    const size_t szSS = (size_t)96 * NCH * 8192 * 2;
    const size_t szRa = szA1 + szW1 + szXB;
    size_t szR = szRa;
    if (szR < szYb) szR = szYb;
    if (szR < szSS) szR = szSS;
    const size_t szHp = szSS;
    const size_t szCU = (size_t)96 * SEQ * 4;

    char* ws = (char*)d_ws;
    size_t off = 0;
    auto alloc = [&](size_t bytes) { char* p = ws + off; off += (bytes + 255) & ~(size_t)255; return p; };

    __hip_bfloat16* W2 = (__hip_bfloat16*)alloc(szW2);
    __hip_bfloat16* Z  = (__hip_bfloat16*)alloc(szZ);
    __hip_bfloat16* XH = (__hip_bfloat16*)alloc(szXH);
    __hip_bfloat16* BM = (__hip_bfloat16*)alloc(szBM);
    __hip_bfloat16* CM = (__hip_bfloat16*)alloc(szCM);
    float* DT = (float*)alloc(szDT);
    float* LA = (float*)alloc(szLA);
    char*  R  = (char*)alloc(szR);
    __hip_bfloat16* A1  = (__hip_bfloat16*)R;
    __hip_bfloat16* W1  = (__hip_bfloat16*)(R + szA1);
    __hip_bfloat16* XBC = (__hip_bfloat16*)(R + szA1 + szW1);
    short* SS = (short*)R;
    __hip_bfloat16* Yb = (__hip_bfloat16*)R;

    short* Hp = (short*)alloc(szHp);
    float* CU = (float*)alloc(szCU);
    if (off > ws_size) return;   // clean fail instead of OOB crash

    // 1. weight converts (float4)
    int n1 = 2 * NPROJ * DMODEL / 4;
    cvt_kernel<<<(n1 + 255) / 256, 256, 0, stream>>>(in_w, W1, n1);
    int n2 = 2 * DMODEL * DINNER / 4;
    cvt_kernel<<<(n2 + 255) / 256, 256, 0, stream>>>(out_w, W2, n2);
    // 2. x -> bf16 (flipped copy for dir 1)
    int n3 = 2 * 4096 * DMODEL / 4;
    prep_x_kernel<<<(n3 + 255) / 256, 256, 0, stream>>>(x, A1);

    // 3. in_proj GEMMs (128-tile BK=64) with routing epilogue; grid.x = M for W reuse
    {
        dim3 grid(4096 / 128, (NPROJ + 127) / 128);
        for (int dir = 0; dir < 2; dir++) {
            gemm_bt<<<grid, 256, 0, stream>>>(A1 + (size_t)dir * 4096 * DMODEL,
                                              W1 + (size_t)dir * NPROJ * DMODEL,
                                              nullptr,
                                              Z   + (size_t)dir * 4096 * DINNER,
                                              XBC + (size_t)dir * 4096 * CONVDIM,
                                              DT  + (size_t)dir * 4096 * NH,
                                              LA  + (size_t)dir * 4096 * NH,
                                              dt_bias + dir * NH,
                                              A_log   + dir * NH,
                                              4096, NPROJ, DMODEL, 2);
        }
    }

    // 4. conv + silu
    conv_kernel<<<4 * 128, 256, 0, stream>>>(XBC, conv_w, conv_b, XH, BM, CM);

    // 5. SSD chunked scan
    ssd1_kernel<<<4 * NH * NCH, 256, 0, stream>>>(XH, BM, DT, LA, SS, CU);
    ssd2_kernel<<<4 * NH * 4, 256, 0, stream>>>(SS, CU, Hp);
    ssd3_kernel<<<4 * NH * NCH, 256, 0, stream>>>(XH, BM, CM, DT, CU, Hp, Yb);

    // 6. gating + RMSNorm (A2 == Z, in-place)
    gate_kernel<<<2 * 4096, 192, 0, stream>>>(Yb, XH, Z, Dp, norm_w, Z);

    // 7. out_proj GEMMs (128-tile BK=64); dir0 overwrites, dir1 flip-adds
    {
        dim3 grid(4096 / 128, DMODEL / 128);
        gemm_bt<<<grid, 256, 0, stream>>>(Z, W2, out,
                                          nullptr, nullptr, nullptr, nullptr, nullptr, nullptr,
                                          4096, DMODEL, DINNER, 0);
        gemm_bt<<<grid, 256, 0, stream>>>(Z + (size_t)4096 * DINNER,
                                          W2 + (size_t)DMODEL * DINNER,
                                          out,
                                          nullptr, nullptr, nullptr, nullptr, nullptr, nullptr,
                                          4096, DMODEL, DINNER, 1);
    }
}

// Round 9
// 389.100 us; speedup vs baseline: 4.4499x; 1.1631x over previous
//
#include <hip/hip_runtime.h>
#include <hip/hip_bf16.h>

typedef __attribute__((ext_vector_type(8))) short short8;
typedef __attribute__((ext_vector_type(4))) short bfx4;
typedef __attribute__((ext_vector_type(4))) float floatx4;

#define SEQ     2048
#define DMODEL  768
#define DINNER  1536
#define DSTATE  128
#define NH      24
#define CONVDIM 1792
#define NPROJ   3352   // 2*DINNER + 2*DSTATE + NH
#define QCH     64     // SSD chunk length
#define NCH     (SEQ / QCH)   // 32 chunks

__device__ inline float bf2f(short s) {
    return __uint_as_float(((unsigned)(unsigned short)s) << 16);
}
__device__ inline short f2bf(float f) {
    __hip_bfloat16 h = __float2bfloat16(f);
    return *reinterpret_cast<short*>(&h);
}
__device__ inline void gl_lds16(const void* g, void* l) {
    __builtin_amdgcn_global_load_lds((const __attribute__((address_space(1))) unsigned int*)g,
                                     (__attribute__((address_space(3))) unsigned int*)l, 16, 0, 0);
}

// ---------------------------------------------------------------- converts (float4)
__global__ __launch_bounds__(256) void cvt_kernel(const float* __restrict__ src,
                                                  __hip_bfloat16* __restrict__ dst, int n4) {
    int i = blockIdx.x * 256 + threadIdx.x;
    if (i >= n4) return;
    float4 v = *(const float4*)(src + (size_t)i * 4);
    bfx4 o = { f2bf(v.x), f2bf(v.y), f2bf(v.z), f2bf(v.w) };
    *(bfx4*)((short*)dst + (size_t)i * 4) = o;
}

// Build A1[dir][b*SEQ+t][k] = bf16(x[b][dir? SEQ-1-t : t][k]); 4 elems/thread
__global__ __launch_bounds__(256) void prep_x_kernel(const float* __restrict__ x,
                                                     __hip_bfloat16* __restrict__ A1) {
    size_t i4 = (size_t)blockIdx.x * 256 + threadIdx.x;
    const size_t total4 = (size_t)2 * 2 * SEQ * DMODEL / 4;
    if (i4 >= total4) return;
    size_t idx = i4 * 4;
    int k = (int)(idx % DMODEL);
    size_t m = idx / DMODEL;
    int dir = (int)(m >> 12);
    int mm  = (int)(m & 4095);
    int b = mm >> 11, t = mm & 2047;
    int ts = dir ? (SEQ - 1 - t) : t;
    float4 v = *(const float4*)(x + ((size_t)(b * SEQ + ts)) * DMODEL + k);
    bfx4 o = { f2bf(v.x), f2bf(v.y), f2bf(v.z), f2bf(v.w) };
    *(bfx4*)((short*)A1 + idx) = o;
}

// ---------------------------------------------------------------- GEMM 128x128, BK=32, double-buffered
// blockIdx.z: dir = z/zdiv, kslice = z%zdiv (split-K). XOR-swizzled global_load_lds staging.
// mode 1: out_proj atomic add (row flipped when dir==1); C pre-zeroed.
// mode 2: in_proj routing epilogue (per-dir output offsets).
__global__ __launch_bounds__(256) void gemm_bt(const __hip_bfloat16* __restrict__ Abase, size_t aStride,
                                               const __hip_bfloat16* __restrict__ Bbase, size_t bStride,
                                               float* __restrict__ C,
                                               __hip_bfloat16* __restrict__ Zb,
                                               __hip_bfloat16* __restrict__ Xb,
                                               float* __restrict__ DT,
                                               float* __restrict__ LA,
                                               const float* __restrict__ dtbias,
                                               const float* __restrict__ Alog,
                                               int M, int N, int K, int zdiv, int mode) {
    __shared__ short As[2][128 * 32];   // 8 KB per buf
    __shared__ short Bs[2][128 * 32];
    int tid = threadIdx.x;
    int w = tid >> 6, lane = tid & 63;
    int q = lane >> 4, mm = lane & 15;
    int wm = w >> 1, wn = w & 1;
    int m0 = blockIdx.x * 128, n0 = blockIdx.y * 128;
    int z = blockIdx.z;
    int dir = z / zdiv, ks = z - dir * zdiv;
    int kl = K / zdiv;
    int kbeg = ks * kl;
    const short* Ag = (const short*)Abase + (size_t)dir * aStride;
    const short* Bg = (const short*)Bbase + (size_t)dir * bStride;

    int srow = lane >> 2;                                     // row within 16-group
    int gch  = (lane & 3) ^ (srow & 3) ^ ((lane >> 4) & 3);   // swizzled global 16B chunk

    floatx4 acc[16];
#pragma unroll
    for (int i = 0; i < 16; i++) acc[i] = (floatx4){0.f, 0.f, 0.f, 0.f};

    int niter = kl / 32;
    auto stage = [&](int buf, int k0) {
#pragma unroll
        for (int j = 0; j < 2; j++) {
            int b16 = (w * 2 + j) * 16;                       // wave-uniform
            int ar = m0 + b16 + srow;                         // M multiple of 128
            gl_lds16(Ag + (size_t)ar * K + kbeg + k0 + gch * 8, (char*)&As[buf][0] + b16 * 64);
            int br = n0 + b16 + srow; if (br > N - 1) br = N - 1;
            gl_lds16(Bg + (size_t)br * K + kbeg + k0 + gch * 8, (char*)&Bs[buf][0] + b16 * 64);
        }
    };
    stage(0, 0);
    int p = q ^ (mm & 3) ^ ((mm >> 2) & 3);                   // read slot (2-way max alias)
    for (int it = 0; it < niter; it++) {
        __syncthreads();                                      // buf[it&1] ready; prev reads done
        if (it + 1 < niter) stage((it + 1) & 1, (it + 1) * 32);
        const short* Ab = &As[it & 1][0];
        const short* Bb = &Bs[it & 1][0];
        short8 af[4], bfr[4];
#pragma unroll
        for (int mb = 0; mb < 4; mb++)
            af[mb] = *(const short8*)&Ab[(wm * 64 + mb * 16 + mm) * 32 + p * 8];
#pragma unroll
        for (int nb = 0; nb < 4; nb++)
            bfr[nb] = *(const short8*)&Bb[(wn * 64 + nb * 16 + mm) * 32 + p * 8];
#pragma unroll
        for (int mb = 0; mb < 4; mb++)
#pragma unroll
            for (int nb = 0; nb < 4; nb++)
                acc[mb * 4 + nb] = __builtin_amdgcn_mfma_f32_16x16x32_bf16(af[mb], bfr[nb], acc[mb * 4 + nb], 0, 0, 0);
    }

    __hip_bfloat16* Zb2 = Zb + (size_t)dir * 4096 * DINNER;
    __hip_bfloat16* Xb2 = Xb + (size_t)dir * 4096 * CONVDIM;
    float* DT2 = DT + (size_t)dir * 4096 * NH;
    float* LA2 = LA + (size_t)dir * 4096 * NH;
    const float* dtb2 = dtbias + dir * NH;
    const float* Al2  = Alog + dir * NH;

#pragma unroll
    for (int mb = 0; mb < 4; mb++) {
#pragma unroll
        for (int nb = 0; nb < 4; nb++) {
            int col = n0 + wn * 64 + nb * 16 + mm;
            if (col >= N) continue;
#pragma unroll
            for (int r = 0; r < 4; r++) {
                int rr = m0 + wm * 64 + mb * 16 + q * 4 + r;
                float v = acc[mb * 4 + nb][r];
                if (mode == 1) {
                    int orow = rr;
                    if (dir) { int b = rr >> 11, t = rr & 2047; orow = (b << 11) + (2047 - t); }
                    atomicAdd(&C[(size_t)orow * N + col], v);
                } else {
                    if (col < DINNER) {
                        Zb2[(size_t)rr * DINNER + col] = __float2bfloat16(v);
                    } else if (col < DINNER + CONVDIM) {
                        Xb2[(size_t)rr * CONVDIM + (col - DINNER)] = __float2bfloat16(v);
                    } else {
                        int hh = col - (DINNER + CONVDIM);
                        float raw = v + dtb2[hh];
                        float dtv = (raw > 20.f) ? raw : log1pf(__expf(raw));
                        float Av  = -__expf(Al2[hh]);
                        DT2[(size_t)rr * NH + hh] = dtv;
                        LA2[(size_t)rr * NH + hh] = dtv * Av;
                    }
                }
            }
        }
    }
}

// ---------------------------------------------------------------- conv (depthwise K=4) + silu
__global__ __launch_bounds__(256) void conv_kernel(const __hip_bfloat16* __restrict__ Xb,
                                                   const float* __restrict__ conv_w,
                                                   const float* __restrict__ conv_b,
                                                   __hip_bfloat16* __restrict__ xh,
                                                   __hip_bfloat16* __restrict__ Bm,
                                                   __hip_bfloat16* __restrict__ Cm) {
    int db  = blockIdx.x >> 7;
    int dir = db >> 1;
    int t0  = (blockIdx.x & 127) * 16;
    int c8  = threadIdx.x * 8;
    if (c8 >= CONVDIM) return;

    float wk[4][8], bs[8];
#pragma unroll
    for (int j = 0; j < 8; j++) {
        bs[j] = conv_b[dir * CONVDIM + c8 + j];
#pragma unroll
        for (int k = 0; k < 4; k++) wk[k][j] = conv_w[((size_t)dir * CONVDIM + c8 + j) * 4 + k];
    }

    const short* xrow = (const short*)Xb + (size_t)db * SEQ * CONVDIM + c8;
    short8 win[4];
    const short8 zer = {0, 0, 0, 0, 0, 0, 0, 0};
#pragma unroll
    for (int k = 0; k < 3; k++) {
        int ts = t0 - 3 + k;
        win[k] = (ts >= 0) ? *(const short8*)(xrow + (size_t)ts * CONVDIM) : zer;
    }

    for (int tt = 0; tt < 16; tt++) {
        int t = t0 + tt;
        win[3] = *(const short8*)(xrow + (size_t)t * CONVDIM);
        short8 outv;
#pragma unroll
        for (int j = 0; j < 8; j++) {
            float acc = bs[j];
#pragma unroll
            for (int k = 0; k < 4; k++) acc += wk[k][j] * bf2f(win[k][j]);
            float sv = acc / (1.f + __expf(-acc));
            outv[j] = f2bf(sv);
        }
        if (c8 < DINNER)
            *(short8*)((short*)xh + (size_t)(db * SEQ + t) * DINNER + c8) = outv;
        else if (c8 < DINNER + DSTATE)
            *(short8*)((short*)Bm + (size_t)(db * SEQ + t) * DSTATE + (c8 - DINNER)) = outv;
        else
            *(short8*)((short*)Cm + (size_t)(db * SEQ + t) * DSTATE + (c8 - DINNER - DSTATE)) = outv;
        win[0] = win[1]; win[1] = win[2]; win[2] = win[3];
    }
}

// ---------------------------------------------------------------- SSD pass 1
__global__ __launch_bounds__(256) void ssd1_kernel(const __hip_bfloat16* __restrict__ XH,
                                                   const __hip_bfloat16* __restrict__ BMh,
                                                   const float* __restrict__ DT,
                                                   const float* __restrict__ LA,
                                                   short* __restrict__ SS,
                                                   float* __restrict__ CUM) {
    int blk = blockIdx.x;
    int ck = blk & 31;
    int dbh = blk >> 5;
    int hh = dbh % NH, db = dbh / NH;
    int base_row = db * SEQ + ck * QCH;

    __shared__ float cum_s[QCH], dt_s[QCH];
    __shared__ short Xt[64][72];
    __shared__ short Bt[128][72];

    int tid = threadIdx.x;
    int lane = tid & 63, w = tid >> 6;
    int q = lane >> 4, mm = lane & 15;

    if (tid < QCH) {
        float la  = LA[(size_t)(base_row + tid) * NH + hh];
        float dtv = DT[(size_t)(base_row + tid) * NH + hh];
        float cs = la;
#pragma unroll
        for (int d = 1; d < 64; d <<= 1) {
            float u = __shfl_up(cs, d);
            if (tid >= d) cs += u;
        }
        cum_s[tid] = cs;
        dt_s[tid] = dtv;
        CUM[(size_t)dbh * SEQ + ck * QCH + tid] = cs;
    }
    __syncthreads();
    float cumL = cum_s[QCH - 1];

    {
        int s2 = (tid & 31) * 2, pb = tid >> 5;
        float f0 = dt_s[s2]     * __expf(cumL - cum_s[s2]);
        float f1 = dt_s[s2 + 1] * __expf(cumL - cum_s[s2 + 1]);
        const short* r0 = (const short*)XH + (size_t)(base_row + s2) * DINNER + hh * 64 + pb * 8;
        const short* r1 = r0 + DINNER;
        short8 x0 = *(const short8*)r0;
        short8 x1 = *(const short8*)r1;
#pragma unroll
        for (int j = 0; j < 8; j++) {
            unsigned lo = (unsigned short)f2bf(f0 * bf2f(x0[j]));
            unsigned hi = (unsigned short)f2bf(f1 * bf2f(x1[j]));
            *(unsigned*)&Xt[pb * 8 + j][s2] = lo | (hi << 16);
        }
    }
    {
        int s2 = (tid & 31) * 2, nb = tid >> 5;
        const short* r0 = (const short*)BMh + (size_t)(base_row + s2) * DSTATE + nb * 16;
        const short* r1 = r0 + DSTATE;
        short8 b0a = *(const short8*)r0,  b0b = *(const short8*)(r0 + 8);
        short8 b1a = *(const short8*)r1,  b1b = *(const short8*)(r1 + 8);
#pragma unroll
        for (int j = 0; j < 8; j++) {
            *(unsigned*)&Bt[nb * 16 + j][s2] =
                (unsigned)(unsigned short)b0a[j] | ((unsigned)(unsigned short)b1a[j] << 16);
            *(unsigned*)&Bt[nb * 16 + 8 + j][s2] =
                (unsigned)(unsigned short)b0b[j] | ((unsigned)(unsigned short)b1b[j] << 16);
        }
    }
    __syncthreads();

    floatx4 acc[8];
#pragma unroll
    for (int i = 0; i < 8; i++) acc[i] = (floatx4){0.f, 0.f, 0.f, 0.f};
#pragma unroll
    for (int kk = 0; kk < 2; kk++) {
        short8 a = *(const short8*)&Xt[w * 16 + mm][kk * 32 + q * 8];
#pragma unroll
        for (int cb = 0; cb < 8; cb++) {
            short8 b = *(const short8*)&Bt[cb * 16 + mm][kk * 32 + q * 8];
            acc[cb] = __builtin_amdgcn_mfma_f32_16x16x32_bf16(a, b, acc[cb], 0, 0, 0);
        }
    }
    short* Sp = SS + (size_t)blk * 8192;
#pragma unroll
    for (int cb = 0; cb < 8; cb++)
#pragma unroll
        for (int r = 0; r < 4; r++)
            Sp[(w * 16 + q * 4 + r) * DSTATE + cb * 16 + mm] = f2bf(acc[cb][r]);
}

// ---------------------------------------------------------------- SSD pass 2: inter-chunk scan
__global__ __launch_bounds__(256) void ssd2_kernel(const short* __restrict__ SS,
                                                   const float* __restrict__ CUM,
                                                   short* __restrict__ Hprev) {
    int blk = blockIdx.x;
    int dbh = blk >> 2, part = blk & 3;
    int off = part * 2048 + threadIdx.x * 8;
    size_t base = (size_t)dbh * NCH * 8192 + off;
    float h[8];
#pragma unroll
    for (int j = 0; j < 8; j++) h[j] = 0.f;
    for (int c = 0; c < NCH; c++) {
        float W = __expf(CUM[(size_t)dbh * SEQ + c * QCH + QCH - 1]);
        size_t p = base + (size_t)c * 8192;
        short8 s = *(const short8*)(SS + p);
        short8 o;
#pragma unroll
        for (int j = 0; j < 8; j++) o[j] = f2bf(h[j]);
        *(short8*)(Hprev + p) = o;
#pragma unroll
        for (int j = 0; j < 8; j++) h[j] = fmaf(h[j], W, bf2f(s[j]));
    }
}

// ---------------------------------------------------------------- SSD pass 3
__global__ __launch_bounds__(256) void ssd3_kernel(const __hip_bfloat16* __restrict__ XH,
                                                   const __hip_bfloat16* __restrict__ BMh,
                                                   const __hip_bfloat16* __restrict__ CMh,
                                                   const float* __restrict__ DT,
                                                   const float* __restrict__ CUM,
                                                   const short* __restrict__ Hprev,
                                                   __hip_bfloat16* __restrict__ Yb) {
    int blk = blockIdx.x;
    int ck = blk & 31;
    int dbh = blk >> 5;
    int hh = dbh % NH, db = dbh / NH;
    int base_row = db * SEQ + ck * QCH;

    __shared__ float cum_s[QCH], dt_s[QCH];
    __shared__ short Ct[64][136];
    __shared__ short G[64][72];
    __shared__ short Xt[64][72];

    int tid = threadIdx.x;
    int lane = tid & 63, w = tid >> 6;
    int q = lane >> 4, mm = lane & 15;

    if (tid < QCH) {
        cum_s[tid] = CUM[(size_t)dbh * SEQ + ck * QCH + tid];
        dt_s[tid]  = DT[(size_t)(base_row + tid) * NH + hh];
    }

    const short* Cg = (const short*)CMh + (size_t)base_row * DSTATE;
    const short* Bg = (const short*)BMh + (size_t)base_row * DSTATE;
    floatx4 P[4];
#pragma unroll
    for (int i = 0; i < 4; i++) P[i] = (floatx4){0.f, 0.f, 0.f, 0.f};
#pragma unroll
    for (int kk = 0; kk < 4; kk++) {
        short8 a = *(const short8*)(Cg + (size_t)(w * 16 + mm) * DSTATE + kk * 32 + q * 8);
#pragma unroll
        for (int cb = 0; cb < 4; cb++) {
            short8 b = *(const short8*)(Bg + (size_t)(cb * 16 + mm) * DSTATE + kk * 32 + q * 8);
            P[cb] = __builtin_amdgcn_mfma_f32_16x16x32_bf16(a, b, P[cb], 0, 0, 0);
        }
    }
    __syncthreads();

    {
        int t = tid & 63, nb4 = tid >> 6;
        float wt = __expf(cum_s[t]);
        const short* src = Cg + (size_t)t * DSTATE + nb4 * 32;
#pragma unroll
        for (int u = 0; u < 2; u++) {
            short8 v = *(const short8*)(src + u * 16);
            short8 v2 = *(const short8*)(src + u * 16 + 8);
#pragma unroll
            for (int j = 0; j < 4; j++) {
                unsigned lo = (unsigned short)f2bf(wt * bf2f(v[2 * j]));
                unsigned hi = (unsigned short)f2bf(wt * bf2f(v[2 * j + 1]));
                *(unsigned*)&Ct[t][nb4 * 32 + u * 16 + 2 * j] = lo | (hi << 16);
                lo = (unsigned short)f2bf(wt * bf2f(v2[2 * j]));
                hi = (unsigned short)f2bf(wt * bf2f(v2[2 * j + 1]));
                *(unsigned*)&Ct[t][nb4 * 32 + u * 16 + 8 + 2 * j] = lo | (hi << 16);
            }
        }
    }
    {
        int s2 = (tid & 31) * 2, pb = tid >> 5;
        const short* r0 = (const short*)XH + (size_t)(base_row + s2) * DINNER + hh * 64 + pb * 8;
        const short* r1 = r0 + DINNER;
        short8 x0 = *(const short8*)r0;
        short8 x1 = *(const short8*)r1;
#pragma unroll
        for (int j = 0; j < 8; j++) {
            *(unsigned*)&Xt[pb * 8 + j][s2] =
                (unsigned)(unsigned short)x0[j] | ((unsigned)(unsigned short)x1[j] << 16);
        }
    }
#pragma unroll
    for (int cb = 0; cb < 4; cb++) {
#pragma unroll
        for (int r = 0; r < 4; r++) {
            int t = w * 16 + q * 4 + r;
            int s = cb * 16 + mm;
            float g = (s <= t) ? P[cb][r] * __expf(cum_s[t] - cum_s[s]) * dt_s[s] : 0.f;
            G[t][s] = f2bf(g);
        }
    }
    __syncthreads();

    floatx4 Y[4];
#pragma unroll
    for (int i = 0; i < 4; i++) Y[i] = (floatx4){0.f, 0.f, 0.f, 0.f};
#pragma unroll
    for (int kk = 0; kk < 2; kk++) {
        short8 a = *(const short8*)&G[w * 16 + mm][kk * 32 + q * 8];
#pragma unroll
        for (int cb = 0; cb < 4; cb++) {
            short8 b = *(const short8*)&Xt[cb * 16 + mm][kk * 32 + q * 8];
            Y[cb] = __builtin_amdgcn_mfma_f32_16x16x32_bf16(a, b, Y[cb], 0, 0, 0);
        }
    }
    const short* Hc = Hprev + (size_t)blk * 8192;
#pragma unroll
    for (int kk = 0; kk < 4; kk++) {
        short8 a = *(const short8*)&Ct[w * 16 + mm][kk * 32 + q * 8];
#pragma unroll
        for (int cb = 0; cb < 4; cb++) {
            short8 b = *(const short8*)(Hc + (size_t)(cb * 16 + mm) * DSTATE + kk * 32 + q * 8);
            Y[cb] = __builtin_amdgcn_mfma_f32_16x16x32_bf16(a, b, Y[cb], 0, 0, 0);
        }
    }
#pragma unroll
    for (int cb = 0; cb < 4; cb++)
#pragma unroll
        for (int r = 0; r < 4; r++)
            Yb[(size_t)(base_row + w * 16 + q * 4 + r) * DINNER + hh * 64 + cb * 16 + mm] =
                __float2bfloat16(Y[cb][r]);
}

// ---------------------------------------------------------------- gating + RMSNorm (192 thr x 8 ch)
__global__ __launch_bounds__(192) void gate_kernel(const __hip_bfloat16* __restrict__ Yb,
                                                   const __hip_bfloat16* __restrict__ xh,
                                                   const __hip_bfloat16* __restrict__ Zb,
                                                   const float* __restrict__ Dp,
                                                   const float* __restrict__ norm_w,
                                                   __hip_bfloat16* __restrict__ A2) {
    int row = blockIdx.x;
    int dir = row >> 12;
    int c8 = threadIdx.x * 8;
    int hd = c8 >> 6;
    const short* yr = (const short*)Yb + (size_t)row * DINNER + c8;
    const short* xr = (const short*)xh + (size_t)row * DINNER + c8;
    const short* zr = (const short*)Zb + (size_t)row * DINNER + c8;

    short8 y8 = *(const short8*)yr;
    short8 x8 = *(const short8*)xr;
    short8 z8 = *(const short8*)zr;
    float Dv = Dp[dir * NH + hd];

    float vals[8];
    float ss = 0.f;
#pragma unroll
    for (int j = 0; j < 8; j++) {
        float v = bf2f(y8[j]) + Dv * bf2f(x8[j]);
        float z = bf2f(z8[j]);
        v *= z / (1.f + __expf(-z));
        vals[j] = v;
        ss += v * v;
    }
#pragma unroll
    for (int off = 32; off; off >>= 1) ss += __shfl_down(ss, off);
    __shared__ float ls[3];
    if ((threadIdx.x & 63) == 0) ls[threadIdx.x >> 6] = ss;
    __syncthreads();
    float tot = ls[0] + ls[1] + ls[2];
    float scale = rsqrtf(tot / (float)DINNER + 1e-5f);

    const float* nw = norm_w + dir * DINNER + c8;
    short8 o;
#pragma unroll
    for (int j = 0; j < 8; j++) o[j] = f2bf(vals[j] * scale * nw[j]);
    *(short8*)((short*)A2 + (size_t)row * DINNER + c8) = o;
}

// ---------------------------------------------------------------- launch
extern "C" void kernel_launch(void* const* d_in, const int* in_sizes, int n_in,
                              void* d_out, int out_size, void* d_ws, size_t ws_size,
                              hipStream_t stream) {
    const float* x        = (const float*)d_in[0];
    const float* in_w     = (const float*)d_in[1];
    const float* conv_w   = (const float*)d_in[2];
    const float* conv_b   = (const float*)d_in[3];
    const float* dt_bias  = (const float*)d_in[4];
    const float* A_log    = (const float*)d_in[5];
    const float* Dp       = (const float*)d_in[6];
    const float* norm_w   = (const float*)d_in[7];
    const float* out_w    = (const float*)d_in[8];
    float* out = (float*)d_out;

    const size_t szW2 = (size_t)2 * DMODEL * DINNER * 2;
    const size_t szZ  = (size_t)8192 * DINNER * 2;
    const size_t szXH = (size_t)8192 * DINNER * 2;
    const size_t szBM = (size_t)8192 * DSTATE * 2;
    const size_t szCM = szBM;
    const size_t szDT = (size_t)8192 * NH * 4;
    const size_t szLA = szDT;
    const size_t szA1 = (size_t)8192 * DMODEL * 2;
    const size_t szW1 = (size_t)2 * NPROJ * DMODEL * 2;
    const size_t szXB = (size_t)8192 * CONVDIM * 2;
    const size_t szYb = (size_t)8192 * DINNER * 2;
    const size_t szSS = (size_t)96 * NCH * 8192 * 2;
    const size_t szRa = szA1 + szW1 + szXB;
    size_t szR = szRa;
    if (szR < szYb) szR = szYb;
    if (szR < szSS) szR = szSS;
    const size_t szHp = szSS;
    const size_t szCU = (size_t)96 * SEQ * 4;

    char* ws = (char*)d_ws;
    size_t off = 0;
    auto alloc = [&](size_t bytes) { char* p = ws + off; off += (bytes + 255) & ~(size_t)255; return p; };

    __hip_bfloat16* W2 = (__hip_bfloat16*)alloc(szW2);
    __hip_bfloat16* Z  = (__hip_bfloat16*)alloc(szZ);
    __hip_bfloat16* XH = (__hip_bfloat16*)alloc(szXH);
    __hip_bfloat16* BM = (__hip_bfloat16*)alloc(szBM);
    __hip_bfloat16* CM = (__hip_bfloat16*)alloc(szCM);
    float* DT = (float*)alloc(szDT);
    float* LA = (float*)alloc(szLA);
    char*  R  = (char*)alloc(szR);
    __hip_bfloat16* A1  = (__hip_bfloat16*)R;
    __hip_bfloat16* W1  = (__hip_bfloat16*)(R + szA1);
    __hip_bfloat16* XBC = (__hip_bfloat16*)(R + szA1 + szW1);
    short* SS = (short*)R;
    __hip_bfloat16* Yb = (__hip_bfloat16*)R;

    short* Hp = (short*)alloc(szHp);
    float* CU = (float*)alloc(szCU);
    if (off > ws_size) return;   // clean fail instead of OOB crash

    // 1. weight converts (float4)
    int n1 = 2 * NPROJ * DMODEL / 4;
    cvt_kernel<<<(n1 + 255) / 256, 256, 0, stream>>>(in_w, W1, n1);
    int n2 = 2 * DMODEL * DINNER / 4;
    cvt_kernel<<<(n2 + 255) / 256, 256, 0, stream>>>(out_w, W2, n2);
    // 2. x -> bf16 (flipped copy for dir 1)
    int n3 = 2 * 4096 * DMODEL / 4;
    prep_x_kernel<<<(n3 + 255) / 256, 256, 0, stream>>>(x, A1);

    // 3. in_proj GEMM: both dirs fused (z = dir), routing epilogue
    {
        dim3 grid(4096 / 128, (NPROJ + 127) / 128, 2);
        gemm_bt<<<grid, 256, 0, stream>>>(A1, (size_t)4096 * DMODEL,
                                          W1, (size_t)NPROJ * DMODEL,
                                          nullptr, Z, XBC, DT, LA, dt_bias, A_log,
                                          4096, NPROJ, DMODEL, 1, 2);
    }

    // 4. conv + silu
    conv_kernel<<<4 * 128, 256, 0, stream>>>(XBC, conv_w, conv_b, XH, BM, CM);

    // 5. SSD chunked scan
    ssd1_kernel<<<4 * NH * NCH, 256, 0, stream>>>(XH, BM, DT, LA, SS, CU);
    ssd2_kernel<<<4 * NH * 4, 256, 0, stream>>>(SS, CU, Hp);
    ssd3_kernel<<<4 * NH * NCH, 256, 0, stream>>>(XH, BM, CM, DT, CU, Hp, Yb);

    // 6. gating + RMSNorm (A2 == Z, in-place)
    gate_kernel<<<2 * 4096, 192, 0, stream>>>(Yb, XH, Z, Dp, norm_w, Z);

    // 7. out_proj: zero-init + single launch (z = dir*2 + kslice), atomic adds, dir1 flipped
    hipMemsetAsync(out, 0, (size_t)4096 * DMODEL * 4, stream);
    {
        dim3 grid(4096 / 128, DMODEL / 128, 4);
        gemm_bt<<<grid, 256, 0, stream>>>(Z, (size_t)4096 * DINNER,
                                          W2, (size_t)DMODEL * DINNER,
                                          out, nullptr, nullptr, nullptr, nullptr, nullptr, nullptr,
                                          4096, DMODEL, DINNER, 2, 1);
    }
}